// Round 19
// baseline (534.815 us; speedup 1.0000x reference)
//
#include <hip/hip_runtime.h>
#include <float.h>
#include <math.h>

// ---------------------------------------------------------------------------
// EdgeGuidedCrossAttention, round 19 = R18 + persistent proj3both:
//   256 persistent blocks (512 thr, 64 KB LDS). Stage Q+K mats once, pull
//   16-row tiles from an atomic work counter (no per-tile barriers), then one
//   barrier + stage V mat + second pass. W staging 300MB->24MB; barriers
//   ~19k->768. A re-read once in pass 2 (L3-served).
// attend: 2-way edge ILP. CSR atomic-free via ranks. K/V fp8. upd bf16.
// Node table (512 B/row): Q bf16 [0,256) | K fp8 [256,384) | V fp8 [384,512).
// ---------------------------------------------------------------------------

typedef __bf16 bf16x8 __attribute__((ext_vector_type(8)));
typedef float  f32x4  __attribute__((ext_vector_type(4)));
typedef float  f32x2  __attribute__((ext_vector_type(2)));
typedef unsigned int u32x2 __attribute__((ext_vector_type(2)));

__device__ __forceinline__ bf16x8 cvt8(const float* p) {
    f32x4 lo = *reinterpret_cast<const f32x4*>(p);
    f32x4 hi = *reinterpret_cast<const f32x4*>(p + 4);
    bf16x8 r;
    r[0] = (__bf16)lo[0]; r[1] = (__bf16)lo[1]; r[2] = (__bf16)lo[2]; r[3] = (__bf16)lo[3];
    r[4] = (__bf16)hi[0]; r[5] = (__bf16)hi[1]; r[6] = (__bf16)hi[2]; r[7] = (__bf16)hi[3];
    return r;
}

__device__ __forceinline__ u32x2 pack_fp8x8(const float* v) {
    int w0 = __builtin_amdgcn_cvt_pk_fp8_f32(v[0], v[1], 0, false);
    w0 = __builtin_amdgcn_cvt_pk_fp8_f32(v[2], v[3], w0, true);
    int w1 = __builtin_amdgcn_cvt_pk_fp8_f32(v[4], v[5], 0, false);
    w1 = __builtin_amdgcn_cvt_pk_fp8_f32(v[6], v[7], w1, true);
    u32x2 r; r[0] = (unsigned)w0; r[1] = (unsigned)w1;
    return r;
}

__device__ __forceinline__ void unpack_fp8x8(u32x2 p, float* out) {
    f32x2 t0 = __builtin_amdgcn_cvt_pk_f32_fp8((int)p[0], false);
    f32x2 t1 = __builtin_amdgcn_cvt_pk_f32_fp8((int)p[0], true);
    f32x2 t2 = __builtin_amdgcn_cvt_pk_f32_fp8((int)p[1], false);
    f32x2 t3 = __builtin_amdgcn_cvt_pk_f32_fp8((int)p[1], true);
    out[0] = t0[0]; out[1] = t0[1]; out[2] = t1[0]; out[3] = t1[1];
    out[4] = t2[0]; out[5] = t2[1]; out[6] = t3[0]; out[7] = t3[1];
}

// Stage one [128][128] bf16 matrix into LDS (256 threads, 8 x 16B each),
// byte ^= ((row&7)<<4) swizzle.
__device__ __forceinline__ void stage_w(const __bf16* __restrict__ Ws, char* wlds, int tid) {
#pragma unroll
    for (int it = 0; it < 8; ++it) {
        int idx = it * 2048 + tid * 8;
        int byteoff = idx * 2;
        int row = byteoff >> 8;
        *reinterpret_cast<bf16x8*>(wlds + (byteoff ^ ((row & 7) << 4)))
            = *reinterpret_cast<const bf16x8*>(Ws + idx);
    }
}
// Same for 512-thread blocks (4 x 16B each).
__device__ __forceinline__ void stage_w512(const __bf16* __restrict__ Ws, char* wlds, int tid) {
#pragma unroll
    for (int it = 0; it < 4; ++it) {
        int idx = it * 4096 + tid * 8;
        int byteoff = idx * 2;
        int row = byteoff >> 8;
        *reinterpret_cast<bf16x8*>(wlds + (byteoff ^ ((row & 7) << 4)))
            = *reinterpret_cast<const bf16x8*>(Ws + idx);
    }
}
__device__ __forceinline__ bf16x8 read_w(const char* wlds, int l15, int lg, int ni, int ks) {
    int row = ni * 16 + l15;
    int off = (row * 256 + ks * 64 + lg * 16) ^ ((row & 7) << 4);
    return *reinterpret_cast<const bf16x8*>(wlds + off);
}

// Fused: blocks [0,64) convert the 8 weight matrices (k-perm for mats 3,7);
// blocks [64,..) compute bias + segment counts + per-edge ranks.
__global__ __launch_bounds__(256) void cvt_bias_count(
    const float* w0, const float* w1, const float* w2, const float* w3,
    const float* w4, const float* w5, const float* w6, const float* w7,
    __bf16* __restrict__ dst,
    const float* __restrict__ ea, const float* __restrict__ We,
    const int* __restrict__ pi, const int* __restrict__ li,
    float* __restrict__ bias, int* __restrict__ counts,
    unsigned* __restrict__ ranks, int Np, int E, int CE)
{
    if (blockIdx.x < 64) {
        const float* srcs[8] = {w0, w1, w2, w3, w4, w5, w6, w7};
        int t = blockIdx.x * 256 + threadIdx.x;
        int mat = t >> 11;
        int base = (t & 2047) * 8;
        const float* s = srcs[mat];
        bool perm = (mat == 3) || (mat == 7);
        __bf16* d = dst + (size_t)mat * 16384;
#pragma unroll
        for (int u = 0; u < 8; ++u) {
            int idx = base + u;
            int row = idx >> 7, c = idx & 127;
            int pos = perm ? ((c & 15) * 8 + (c >> 4)) : c;
            d[row * 128 + pos] = (__bf16)s[idx];
        }
        return;
    }
    int e = (blockIdx.x - 64) * 256 + threadIdx.x;
    if (e >= E) return;
    const float2* row = reinterpret_cast<const float2*>(ea + (size_t)e * CE);
    float acc = 0.f;
    int h = CE >> 1;
    for (int c = 0; c < h; ++c) {
        float2 v = row[c];
        acc += v.x * We[2 * c] + v.y * We[2 * c + 1];
    }
    if (CE & 1) acc += ea[(size_t)e * CE + CE - 1] * We[CE - 1];
    bias[e] = acc;
    int r0 = atomicAdd(&counts[pi[e]], 1);
    int r1 = atomicAdd(&counts[Np + li[e]], 1);
    ranks[e] = (unsigned)(r0 & 0xFFFF) | ((unsigned)r1 << 16);
}

__global__ __launch_bounds__(256) void scan1(
    const int* __restrict__ counts, int* __restrict__ offs,
    int* __restrict__ bsums, int N)
{
    int idx = blockIdx.x * 256 + threadIdx.x;
    int v = (idx < N) ? counts[idx] : 0;
    int lane = threadIdx.x & 63, w = threadIdx.x >> 6;
    int x = v;
#pragma unroll
    for (int d = 1; d < 64; d <<= 1) {
        int y = __shfl_up(x, d);
        if (lane >= d) x += y;
    }
    __shared__ int wsum[4];
    if (lane == 63) wsum[w] = x;
    __syncthreads();
    int add = 0;
    for (int i = 0; i < w; ++i) add += wsum[i];
    x += add;
    if (idx < N) offs[idx] = x - v;
    if (threadIdx.x == 255) bsums[blockIdx.x] = x;
}

// scan3 with scan2 folded in: each block computes its prefix over raw bsums.
__global__ __launch_bounds__(256) void scan3(
    int* __restrict__ offs, const int* __restrict__ bsums, int N, int total)
{
    int b = blockIdx.x, t = threadIdx.x;
    int s = 0;
    for (int i = t; i < b; i += 256) s += bsums[i];
#pragma unroll
    for (int d = 1; d < 64; d <<= 1) s += __shfl_xor(s, d);
    __shared__ int ws_[4];
    if ((t & 63) == 0) ws_[t >> 6] = s;
    __syncthreads();
    int pre = ws_[0] + ws_[1] + ws_[2] + ws_[3];
    int idx = b * 256 + t;
    if (idx < N) offs[idx] += pre;
    if (idx == 0) offs[N] = total;
}

// Atomic-free fill: position = offs[seg] + precomputed rank. 4B records
// {other:24b | bias fp8:8b}.
__global__ __launch_bounds__(256) void fill2(
    const int* __restrict__ pi, const int* __restrict__ li,
    const float* __restrict__ bias, const unsigned* __restrict__ ranks,
    const int* __restrict__ offs, unsigned* __restrict__ elist, int Np, int E)
{
    int e = blockIdx.x * 256 + threadIdx.x;
    if (e >= E) return;
    int p = pi[e], l = li[e];
    unsigned rk = ranks[e];
    int w = __builtin_amdgcn_cvt_pk_fp8_f32(bias[e], 0.f, 0, false);
    unsigned b8 = (unsigned)w & 0xFFu;
    elist[offs[p] + (rk & 0xFFFFu)]  = ((unsigned)l << 8) | b8;
    elist[offs[Np + l] + (rk >> 16)] = ((unsigned)p << 8) | b8;
}

// Persistent fused QKV projection. 256 blocks x 512 thr; blocks [0,NBP) pro,
// rest lig. Stage Q+K mats (64 KB) once, atomic-counter tile loop (16 rows
// per tile, no barriers), then stage V mat + second tile loop.
__global__ __launch_bounds__(512) void proj3both(
    const float* __restrict__ Xp, const float* __restrict__ Xl,
    const __bf16* __restrict__ W16,
    const float* __restrict__ bq_p, const float* __restrict__ bk_p, const float* __restrict__ bv_p,
    const float* __restrict__ bq_l, const float* __restrict__ bk_l, const float* __restrict__ bv_l,
    char* __restrict__ QKVp, char* __restrict__ QKVl,
    int Np, int Nl, int NBP, int* __restrict__ tctr)
{
    __shared__ char wlds[65536];
    int tid = threadIdx.x;
    int lane = tid & 63;
    int l15 = lane & 15, lg = (lane >> 4) & 3;

    const float* A; const __bf16 *Wm0, *Wm1, *Wm2;
    const float *bQ, *bK, *bV; char* QKV; int M; int* c1; int* c2;
    if ((int)blockIdx.x < NBP) {
        A = Xp; M = Np;
        Wm0 = W16 + 0 * 16384; Wm1 = W16 + 5 * 16384; Wm2 = W16 + 6 * 16384;
        bQ = bq_p; bK = bk_p; bV = bv_p; QKV = QKVp;
        c1 = tctr + 0; c2 = tctr + 1;
    } else {
        A = Xl; M = Nl;
        Wm0 = W16 + 4 * 16384; Wm1 = W16 + 1 * 16384; Wm2 = W16 + 2 * 16384;
        bQ = bq_l; bK = bk_l; bV = bv_l; QKV = QKVl;
        c1 = tctr + 2; c2 = tctr + 3;
    }
    const int nt = (M + 15) >> 4;

    stage_w512(Wm0, wlds, tid);
    stage_w512(Wm1, wlds + 32768, tid);
    __syncthreads();

    float bQc[8], bKc[8], bVc[8];
#pragma unroll
    for (int ni = 0; ni < 8; ++ni) {
        bQc[ni] = bQ[ni * 16 + l15];
        bKc[ni] = bK[ni * 16 + l15];
        bVc[ni] = bV[ni * 16 + l15];
    }

    // pass 1: Q (bf16) + K (fp8)
    for (;;) {
        int t = 0;
        if (lane == 0) t = atomicAdd(c1, 1);
        t = __shfl(t, 0);
        if (t >= nt) break;
        int wrow = t << 4;
        int r0 = wrow + l15; if (r0 > M - 1) r0 = M - 1;
        const float* Arow0 = A + (size_t)r0 * 128 + lg * 8;
        bf16x8 a0[4];
#pragma unroll
        for (int ks = 0; ks < 4; ++ks) a0[ks] = cvt8(Arow0 + ks * 32);

#pragma unroll
        for (int mat = 0; mat < 2; ++mat) {
            const char* wl = wlds + mat * 32768;
            f32x4 acc[8] = {};
#pragma unroll
            for (int ks = 0; ks < 4; ++ks) {
#pragma unroll
                for (int ni = 0; ni < 8; ++ni)
                    acc[ni] = __builtin_amdgcn_mfma_f32_16x16x32_bf16(
                        a0[ks], read_w(wl, l15, lg, ni, ks), acc[ni], 0, 0, 0);
            }
#pragma unroll
            for (int r = 0; r < 4; ++r) {
                int row = wrow + lg * 4 + r;
                if (row < M) {
                    float v[8];          // col 16*ni+l15 -> stored pos l15*8+ni
#pragma unroll
                    for (int ni = 0; ni < 8; ++ni)
                        v[ni] = acc[ni][r] + (mat == 0 ? bQc[ni] : bKc[ni]);
                    char* rowb = QKV + (size_t)row * 512;
                    if (mat == 0) {
                        bf16x8 o;
#pragma unroll
                        for (int ni = 0; ni < 8; ++ni) o[ni] = (__bf16)v[ni];
                        *reinterpret_cast<bf16x8*>(rowb + l15 * 16) = o;
                    } else {
                        *reinterpret_cast<u32x2*>(rowb + 256 + l15 * 8) = pack_fp8x8(v);
                    }
                }
            }
        }
    }

    __syncthreads();                 // all pass-1 reads of wlds done
    stage_w512(Wm2, wlds, tid);
    __syncthreads();

    // pass 2: V (fp8); A re-read (L3-served)
    for (;;) {
        int t = 0;
        if (lane == 0) t = atomicAdd(c2, 1);
        t = __shfl(t, 0);
        if (t >= nt) break;
        int wrow = t << 4;
        int r0 = wrow + l15; if (r0 > M - 1) r0 = M - 1;
        const float* Arow0 = A + (size_t)r0 * 128 + lg * 8;
        bf16x8 a0[4];
#pragma unroll
        for (int ks = 0; ks < 4; ++ks) a0[ks] = cvt8(Arow0 + ks * 32);

        f32x4 acc[8] = {};
#pragma unroll
        for (int ks = 0; ks < 4; ++ks) {
#pragma unroll
            for (int ni = 0; ni < 8; ++ni)
                acc[ni] = __builtin_amdgcn_mfma_f32_16x16x32_bf16(
                    a0[ks], read_w(wlds, l15, lg, ni, ks), acc[ni], 0, 0, 0);
        }
#pragma unroll
        for (int r = 0; r < 4; ++r) {
            int row = wrow + lg * 4 + r;
            if (row < M) {
                float v[8];
#pragma unroll
                for (int ni = 0; ni < 8; ++ni) v[ni] = acc[ni][r] + bVc[ni];
                *reinterpret_cast<u32x2*>(QKV + (size_t)row * 512 + 384 + l15 * 8)
                    = pack_fp8x8(v);
            }
        }
    }
}

// One 16-lane group per target node (4 nodes/wave); 2-way edge ILP unroll.
// Lane holds 8 (permuted) dims; K,V fp8; 4B edge records; clamp at 60.
__global__ __launch_bounds__(256) void attend(
    const char* __restrict__ QKVp, const char* __restrict__ QKVl,
    const unsigned* __restrict__ elist, const int* __restrict__ offs,
    __bf16* __restrict__ upd_pro, __bf16* __restrict__ upd_lig,
    int Np, int Ntot, float scale)
{
    int node = blockIdx.x * 16 + (threadIdx.x >> 4);
    if (node >= Ntot) return;
    int l = threadIdx.x & 15;
    const char* Qrow; const char* KV; __bf16* upd;
    if (node < Np) {
        Qrow = QKVp + (size_t)node * 512; KV = QKVl;
        upd = upd_pro + (size_t)node * 128;
    } else {
        int n = node - Np;
        Qrow = QKVl + (size_t)n * 512; KV = QKVp;
        upd = upd_lig + (size_t)n * 128;
    }
    bf16x8 qv = *reinterpret_cast<const bf16x8*>(Qrow + l * 16);
    float q[8];
#pragma unroll
    for (int j = 0; j < 8; ++j) q[j] = (float)qv[j];

    int beg = offs[node], end = offs[node + 1];
    float d = 0.f;
    float acc[8] = {};
    int i = beg;
    for (; i + 1 < end; i += 2) {
        unsigned rec0 = elist[i], rec1 = elist[i + 1];
        const char* row0 = KV + (size_t)(rec0 >> 8) * 512;
        const char* row1 = KV + (size_t)(rec1 >> 8) * 512;
        u32x2 kk0 = *reinterpret_cast<const u32x2*>(row0 + 256 + l * 8);
        u32x2 vp0 = *reinterpret_cast<const u32x2*>(row0 + 384 + l * 8);
        u32x2 kk1 = *reinterpret_cast<const u32x2*>(row1 + 256 + l * 8);
        u32x2 vp1 = *reinterpret_cast<const u32x2*>(row1 + 384 + l * 8);
        float kf0[8], vf0[8], kf1[8], vf1[8];
        unpack_fp8x8(kk0, kf0); unpack_fp8x8(vp0, vf0);
        unpack_fp8x8(kk1, kf1); unpack_fp8x8(vp1, vf1);
        float dot0 = 0.f, dot1 = 0.f;
#pragma unroll
        for (int j = 0; j < 8; ++j) { dot0 += q[j] * kf0[j]; dot1 += q[j] * kf1[j]; }
#pragma unroll
        for (int t = 1; t < 16; t <<= 1) {
            dot0 += __shfl_xor(dot0, t, 16);
            dot1 += __shfl_xor(dot1, t, 16);
        }
        f32x2 b0 = __builtin_amdgcn_cvt_pk_f32_fp8((int)(rec0 & 0xFFu), false);
        f32x2 b1 = __builtin_amdgcn_cvt_pk_f32_fp8((int)(rec1 & 0xFFu), false);
        float p0 = __expf(fminf(dot0 * scale + b0[0], 60.f));
        float p1 = __expf(fminf(dot1 * scale + b1[0], 60.f));
        d += p0 + p1;
#pragma unroll
        for (int j = 0; j < 8; ++j) acc[j] += p0 * vf0[j] + p1 * vf1[j];
    }
    if (i < end) {
        unsigned rec = elist[i];
        const char* row = KV + (size_t)(rec >> 8) * 512;
        u32x2 kk = *reinterpret_cast<const u32x2*>(row + 256 + l * 8);
        u32x2 vp = *reinterpret_cast<const u32x2*>(row + 384 + l * 8);
        float kf[8], vf[8];
        unpack_fp8x8(kk, kf); unpack_fp8x8(vp, vf);
        float dot = 0.f;
#pragma unroll
        for (int j = 0; j < 8; ++j) dot += q[j] * kf[j];
#pragma unroll
        for (int t = 1; t < 16; t <<= 1) dot += __shfl_xor(dot, t, 16);
        f32x2 bt = __builtin_amdgcn_cvt_pk_f32_fp8((int)(rec & 0xFFu), false);
        float p = __expf(fminf(dot * scale + bt[0], 60.f));
        d += p;
#pragma unroll
        for (int j = 0; j < 8; ++j) acc[j] += p * vf[j];
    }
    float inv = 1.f / (d + 1e-8f);
    bf16x8 o;
#pragma unroll
    for (int j = 0; j < 8; ++j) o[j] = (__bf16)(acc[j] * inv);
    *reinterpret_cast<bf16x8*>(upd + l * 8) = o;   // permuted bf16 layout
}

// C = LayerNorm(X + A @ Wo^T + b), both node sets (64-row blocks, 256 thr).
// A (upd) bf16 with k-permuted cols; Wo16's k-dim identically permuted.
__global__ __launch_bounds__(256) void gemm_ln_both(
    const __bf16* __restrict__ upd_pro, const __bf16* __restrict__ upd_lig,
    const float* __restrict__ Xp, const float* __restrict__ Xl,
    const __bf16* __restrict__ W16,
    const float* __restrict__ bo_p, const float* __restrict__ g_p, const float* __restrict__ be_p,
    const float* __restrict__ bo_l, const float* __restrict__ g_l, const float* __restrict__ be_l,
    float* __restrict__ out_pro, float* __restrict__ out_lig,
    int Np, int Nl, int nbp)
{
    __shared__ char wlds[32768];
    int bid = blockIdx.x;
    int tid = threadIdx.x;
    int lane = tid & 63, wv = tid >> 6;
    int l15 = lane & 15, lg = lane >> 4;

    const __bf16* A; const float* X; const __bf16* Wo;
    const float *b, *g, *be_; float* C; int M, wrow;
    if (bid < nbp) {
        A = upd_pro; X = Xp; Wo = W16 + 3 * 16384;
        b = bo_p; g = g_p; be_ = be_p; C = out_pro; M = Np; wrow = bid * 64 + wv * 16;
    } else {
        A = upd_lig; X = Xl; Wo = W16 + 7 * 16384;
        b = bo_l; g = g_l; be_ = be_l; C = out_lig; M = Nl; wrow = (bid - nbp) * 64 + wv * 16;
    }
    stage_w(Wo, wlds, tid);

    int r0 = wrow + l15; if (r0 > M - 1) r0 = M - 1;
    const __bf16* Arow0 = A + (size_t)r0 * 128 + lg * 8;
    bf16x8 a0[4];
#pragma unroll
    for (int ks = 0; ks < 4; ++ks)
        a0[ks] = *reinterpret_cast<const bf16x8*>(Arow0 + ks * 32);
    __syncthreads();

    f32x4 acc[8] = {};
#pragma unroll
    for (int ks = 0; ks < 4; ++ks) {
#pragma unroll
        for (int ni = 0; ni < 8; ++ni)
            acc[ni] = __builtin_amdgcn_mfma_f32_16x16x32_bf16(
                a0[ks], read_w(wlds, l15, lg, ni, ks), acc[ni], 0, 0, 0);
    }

    float bcol[8], gcol[8], becol[8];
#pragma unroll
    for (int ni = 0; ni < 8; ++ni) {
        bcol[ni]  = b[ni * 16 + l15];
        gcol[ni]  = g[ni * 16 + l15];
        becol[ni] = be_[ni * 16 + l15];
    }

#pragma unroll
    for (int r = 0; r < 4; ++r) {
        int row = wrow + lg * 4 + r;
        bool ok = row < M;
        int rowc = ok ? row : M - 1;
        float v[8];
#pragma unroll
        for (int ni = 0; ni < 8; ++ni) v[ni] = acc[ni][r] + bcol[ni];
        const float* Xr = X + (size_t)rowc * 128 + l15;
        float s1 = 0.f, s2 = 0.f;
#pragma unroll
        for (int ni = 0; ni < 8; ++ni) {
            v[ni] += Xr[ni * 16];
            s1 += v[ni]; s2 += v[ni] * v[ni];
        }
#pragma unroll
        for (int d = 1; d < 16; d <<= 1) {
            s1 += __shfl_xor(s1, d);
            s2 += __shfl_xor(s2, d);
        }
        float mu = s1 * 0.0078125f;
        float var = s2 * 0.0078125f - mu * mu;
        float rstd = rsqrtf(var + 1e-5f);
        if (ok) {
            float* Cr = C + (size_t)row * 128 + l15;
#pragma unroll
            for (int ni = 0; ni < 8; ++ni)
                Cr[ni * 16] = (v[ni] - mu) * rstd * gcol[ni] + becol[ni];
        }
    }
}

static inline int cdiv(int a, int b) { return (a + b - 1) / b; }

extern "C" void kernel_launch(void* const* d_in, const int* in_sizes, int n_in,
                              void* d_out, int out_size, void* d_ws, size_t ws_size,
                              hipStream_t stream)
{
    const float* pro_x  = (const float*)d_in[0];
    const float* lig_x  = (const float*)d_in[1];
    const int*   ei     = (const int*)d_in[2];
    const float* ea     = (const float*)d_in[3];
    const float* Wq_pro = (const float*)d_in[4];  const float* bq_pro = (const float*)d_in[5];
    const float* Wk_lig = (const float*)d_in[6];  const float* bk_lig = (const float*)d_in[7];
    const float* Wv_lig = (const float*)d_in[8];  const float* bv_lig = (const float*)d_in[9];
    const float* Wq_lig = (const float*)d_in[10]; const float* bq_lig = (const float*)d_in[11];
    const float* Wk_pro = (const float*)d_in[12]; const float* bk_pro = (const float*)d_in[13];
    const float* Wv_pro = (const float*)d_in[14]; const float* bv_pro = (const float*)d_in[15];
    const float* We     = (const float*)d_in[16];
    const float* Wo_pro = (const float*)d_in[17]; const float* bo_pro = (const float*)d_in[18];
    const float* Wo_lig = (const float*)d_in[19]; const float* bo_lig = (const float*)d_in[20];
    const float* g_pro  = (const float*)d_in[21]; const float* be_pro = (const float*)d_in[22];
    const float* g_lig  = (const float*)d_in[23]; const float* be_lig = (const float*)d_in[24];

    const int Np = in_sizes[0] / 128;
    const int Nl = in_sizes[1] / 128;
    const int E  = in_sizes[2] / 2;
    const int CE = in_sizes[3] / E;
    const int Nmax = Np > Nl ? Np : Nl;
    const int Ntot = Np + Nl;
    const int* pi = ei;
    const int* li = ei + E;

    float* out_pro = (float*)d_out;
    float* out_lig = out_pro + (size_t)Np * 128;

    float* ws = (float*)d_ws;
    size_t o = 0;
    char* QKVp = (char*)(ws + o); o += (size_t)Nmax * 128;       // [N][512B]
    char* QKVl = (char*)(ws + o); o += (size_t)Nmax * 128;
    float* bias = ws + o;   o += (size_t)E;
    unsigned* ranks = (unsigned*)(ws + o); o += (size_t)E;
    unsigned* elist = (unsigned*)(ws + o); o += 2 * (size_t)E;   // 2E x 4B
    int* counts = (int*)(ws + o); o += (size_t)Ntot + 8;
    int* offs   = (int*)(ws + o); o += (size_t)Ntot + 8;
    int* bsums  = (int*)(ws + o); o += 4096;
    __bf16* W16 = (__bf16*)(ws + o); o += 8 * 16384 / 2;         // [8][128][128] bf16
    __bf16* upd = (__bf16*)(ws + o); o += (size_t)Ntot * 64;     // permuted bf16
    __bf16* upd_pro = upd;
    __bf16* upd_lig = upd + (size_t)Np * 128;
    int* tctr = counts + Ntot + 1;   // 4 tile counters, zeroed by the memset
    (void)ws_size; (void)n_in; (void)out_size;

    const float scale = 1.0f / sqrtf(128.0f);
    const int nEB = cdiv(E, 256);

    (void)hipMemsetAsync(counts, 0, (size_t)(Ntot + 8) * sizeof(int), stream);
    // W16 order: 0=Wq_pro 1=Wk_lig 2=Wv_lig 3=Wo_pro 4=Wq_lig 5=Wk_pro 6=Wv_pro 7=Wo_lig
    cvt_bias_count<<<64 + nEB, 256, 0, stream>>>(
        Wq_pro, Wk_lig, Wv_lig, Wo_pro, Wq_lig, Wk_pro, Wv_pro, Wo_lig, W16,
        ea, We, pi, li, bias, counts, ranks, Np, E, CE);

    const int nb1 = cdiv(Ntot, 256);
    scan1<<<nb1, 256, 0, stream>>>(counts, offs, bsums, Ntot);
    scan3<<<nb1, 256, 0, stream>>>(offs, bsums, Ntot, 2 * E);
    fill2<<<nEB, 256, 0, stream>>>(pi, li, bias, ranks, offs, elist, Np, E);

    const int NBP = 128, NBL = 128;   // persistent proj blocks per species
    proj3both<<<NBP + NBL, 512, 0, stream>>>(pro_x, lig_x, W16,
        bq_pro, bk_pro, bv_pro, bq_lig, bk_lig, bv_lig,
        QKVp, QKVl, Np, Nl, NBP, tctr);

    attend<<<cdiv(Ntot, 16), 256, 0, stream>>>(QKVp, QKVl, elist, offs,
        upd_pro, upd_lig, Np, Ntot, scale);

    const int nbp = cdiv(Np, 64), nbl = cdiv(Nl, 64);
    gemm_ln_both<<<nbp + nbl, 256, 0, stream>>>(upd_pro, upd_lig,
        pro_x, lig_x, W16, bo_pro, g_pro, be_pro, bo_lig, g_lig, be_lig,
        out_pro, out_lig, Np, Nl, nbp);
}

// Round 20
// 330.303 us; speedup vs baseline: 1.6192x; 1.6192x over previous
//
#include <hip/hip_runtime.h>
#include <float.h>
#include <math.h>

// ---------------------------------------------------------------------------
// EdgeGuidedCrossAttention, round 20 = R18 + persistent proj3both with
// STATIC strided tile assignment (R19's atomic tile counter serialized the
// kernel; tiles are equal-cost so static partitioning is balanced and free).
// 256 persistent blocks (512 thr, 64 KB LDS): stage Q+K mats once, strided
// tile loop (16 rows/tile, no barriers), one barrier, stage V mat, pass 2.
// attend: 2-way edge ILP. CSR atomic-free via ranks. K/V fp8. upd bf16.
// Node table (512 B/row): Q bf16 [0,256) | K fp8 [256,384) | V fp8 [384,512).
// ---------------------------------------------------------------------------

typedef __bf16 bf16x8 __attribute__((ext_vector_type(8)));
typedef float  f32x4  __attribute__((ext_vector_type(4)));
typedef float  f32x2  __attribute__((ext_vector_type(2)));
typedef unsigned int u32x2 __attribute__((ext_vector_type(2)));

__device__ __forceinline__ bf16x8 cvt8(const float* p) {
    f32x4 lo = *reinterpret_cast<const f32x4*>(p);
    f32x4 hi = *reinterpret_cast<const f32x4*>(p + 4);
    bf16x8 r;
    r[0] = (__bf16)lo[0]; r[1] = (__bf16)lo[1]; r[2] = (__bf16)lo[2]; r[3] = (__bf16)lo[3];
    r[4] = (__bf16)hi[0]; r[5] = (__bf16)hi[1]; r[6] = (__bf16)hi[2]; r[7] = (__bf16)hi[3];
    return r;
}

__device__ __forceinline__ u32x2 pack_fp8x8(const float* v) {
    int w0 = __builtin_amdgcn_cvt_pk_fp8_f32(v[0], v[1], 0, false);
    w0 = __builtin_amdgcn_cvt_pk_fp8_f32(v[2], v[3], w0, true);
    int w1 = __builtin_amdgcn_cvt_pk_fp8_f32(v[4], v[5], 0, false);
    w1 = __builtin_amdgcn_cvt_pk_fp8_f32(v[6], v[7], w1, true);
    u32x2 r; r[0] = (unsigned)w0; r[1] = (unsigned)w1;
    return r;
}

__device__ __forceinline__ void unpack_fp8x8(u32x2 p, float* out) {
    f32x2 t0 = __builtin_amdgcn_cvt_pk_f32_fp8((int)p[0], false);
    f32x2 t1 = __builtin_amdgcn_cvt_pk_f32_fp8((int)p[0], true);
    f32x2 t2 = __builtin_amdgcn_cvt_pk_f32_fp8((int)p[1], false);
    f32x2 t3 = __builtin_amdgcn_cvt_pk_f32_fp8((int)p[1], true);
    out[0] = t0[0]; out[1] = t0[1]; out[2] = t1[0]; out[3] = t1[1];
    out[4] = t2[0]; out[5] = t2[1]; out[6] = t3[0]; out[7] = t3[1];
}

// Stage one [128][128] bf16 matrix into LDS (256 threads, 8 x 16B each),
// byte ^= ((row&7)<<4) swizzle.
__device__ __forceinline__ void stage_w(const __bf16* __restrict__ Ws, char* wlds, int tid) {
#pragma unroll
    for (int it = 0; it < 8; ++it) {
        int idx = it * 2048 + tid * 8;
        int byteoff = idx * 2;
        int row = byteoff >> 8;
        *reinterpret_cast<bf16x8*>(wlds + (byteoff ^ ((row & 7) << 4)))
            = *reinterpret_cast<const bf16x8*>(Ws + idx);
    }
}
// Same for 512-thread blocks (4 x 16B each).
__device__ __forceinline__ void stage_w512(const __bf16* __restrict__ Ws, char* wlds, int tid) {
#pragma unroll
    for (int it = 0; it < 4; ++it) {
        int idx = it * 4096 + tid * 8;
        int byteoff = idx * 2;
        int row = byteoff >> 8;
        *reinterpret_cast<bf16x8*>(wlds + (byteoff ^ ((row & 7) << 4)))
            = *reinterpret_cast<const bf16x8*>(Ws + idx);
    }
}
__device__ __forceinline__ bf16x8 read_w(const char* wlds, int l15, int lg, int ni, int ks) {
    int row = ni * 16 + l15;
    int off = (row * 256 + ks * 64 + lg * 16) ^ ((row & 7) << 4);
    return *reinterpret_cast<const bf16x8*>(wlds + off);
}

// Fused: blocks [0,64) convert the 8 weight matrices (k-perm for mats 3,7);
// blocks [64,..) compute bias + segment counts + per-edge ranks.
__global__ __launch_bounds__(256) void cvt_bias_count(
    const float* w0, const float* w1, const float* w2, const float* w3,
    const float* w4, const float* w5, const float* w6, const float* w7,
    __bf16* __restrict__ dst,
    const float* __restrict__ ea, const float* __restrict__ We,
    const int* __restrict__ pi, const int* __restrict__ li,
    float* __restrict__ bias, int* __restrict__ counts,
    unsigned* __restrict__ ranks, int Np, int E, int CE)
{
    if (blockIdx.x < 64) {
        const float* srcs[8] = {w0, w1, w2, w3, w4, w5, w6, w7};
        int t = blockIdx.x * 256 + threadIdx.x;
        int mat = t >> 11;
        int base = (t & 2047) * 8;
        const float* s = srcs[mat];
        bool perm = (mat == 3) || (mat == 7);
        __bf16* d = dst + (size_t)mat * 16384;
#pragma unroll
        for (int u = 0; u < 8; ++u) {
            int idx = base + u;
            int row = idx >> 7, c = idx & 127;
            int pos = perm ? ((c & 15) * 8 + (c >> 4)) : c;
            d[row * 128 + pos] = (__bf16)s[idx];
        }
        return;
    }
    int e = (blockIdx.x - 64) * 256 + threadIdx.x;
    if (e >= E) return;
    const float2* row = reinterpret_cast<const float2*>(ea + (size_t)e * CE);
    float acc = 0.f;
    int h = CE >> 1;
    for (int c = 0; c < h; ++c) {
        float2 v = row[c];
        acc += v.x * We[2 * c] + v.y * We[2 * c + 1];
    }
    if (CE & 1) acc += ea[(size_t)e * CE + CE - 1] * We[CE - 1];
    bias[e] = acc;
    int r0 = atomicAdd(&counts[pi[e]], 1);
    int r1 = atomicAdd(&counts[Np + li[e]], 1);
    ranks[e] = (unsigned)(r0 & 0xFFFF) | ((unsigned)r1 << 16);
}

__global__ __launch_bounds__(256) void scan1(
    const int* __restrict__ counts, int* __restrict__ offs,
    int* __restrict__ bsums, int N)
{
    int idx = blockIdx.x * 256 + threadIdx.x;
    int v = (idx < N) ? counts[idx] : 0;
    int lane = threadIdx.x & 63, w = threadIdx.x >> 6;
    int x = v;
#pragma unroll
    for (int d = 1; d < 64; d <<= 1) {
        int y = __shfl_up(x, d);
        if (lane >= d) x += y;
    }
    __shared__ int wsum[4];
    if (lane == 63) wsum[w] = x;
    __syncthreads();
    int add = 0;
    for (int i = 0; i < w; ++i) add += wsum[i];
    x += add;
    if (idx < N) offs[idx] = x - v;
    if (threadIdx.x == 255) bsums[blockIdx.x] = x;
}

// scan3 with scan2 folded in: each block computes its prefix over raw bsums.
__global__ __launch_bounds__(256) void scan3(
    int* __restrict__ offs, const int* __restrict__ bsums, int N, int total)
{
    int b = blockIdx.x, t = threadIdx.x;
    int s = 0;
    for (int i = t; i < b; i += 256) s += bsums[i];
#pragma unroll
    for (int d = 1; d < 64; d <<= 1) s += __shfl_xor(s, d);
    __shared__ int ws_[4];
    if ((t & 63) == 0) ws_[t >> 6] = s;
    __syncthreads();
    int pre = ws_[0] + ws_[1] + ws_[2] + ws_[3];
    int idx = b * 256 + t;
    if (idx < N) offs[idx] += pre;
    if (idx == 0) offs[N] = total;
}

// Atomic-free fill: position = offs[seg] + precomputed rank. 4B records
// {other:24b | bias fp8:8b}.
__global__ __launch_bounds__(256) void fill2(
    const int* __restrict__ pi, const int* __restrict__ li,
    const float* __restrict__ bias, const unsigned* __restrict__ ranks,
    const int* __restrict__ offs, unsigned* __restrict__ elist, int Np, int E)
{
    int e = blockIdx.x * 256 + threadIdx.x;
    if (e >= E) return;
    int p = pi[e], l = li[e];
    unsigned rk = ranks[e];
    int w = __builtin_amdgcn_cvt_pk_fp8_f32(bias[e], 0.f, 0, false);
    unsigned b8 = (unsigned)w & 0xFFu;
    elist[offs[p] + (rk & 0xFFFFu)]  = ((unsigned)l << 8) | b8;
    elist[offs[Np + l] + (rk >> 16)] = ((unsigned)p << 8) | b8;
}

// Persistent fused QKV projection, STATIC strided tiles (no atomics).
// 256 blocks x 512 thr; blocks [0,NBP) pro, rest lig. Stage Q+K (64 KB)
// once, strided 16-row tile loop, barrier, stage V, second loop.
__global__ __launch_bounds__(512) void proj3both(
    const float* __restrict__ Xp, const float* __restrict__ Xl,
    const __bf16* __restrict__ W16,
    const float* __restrict__ bq_p, const float* __restrict__ bk_p, const float* __restrict__ bv_p,
    const float* __restrict__ bq_l, const float* __restrict__ bk_l, const float* __restrict__ bv_l,
    char* __restrict__ QKVp, char* __restrict__ QKVl,
    int Np, int Nl, int NBP, int NBL)
{
    __shared__ char wlds[65536];
    int tid = threadIdx.x;
    int lane = tid & 63;
    int l15 = lane & 15, lg = (lane >> 4) & 3;
    int wv = tid >> 6;                     // 8 waves/block

    const float* A; const __bf16 *Wm0, *Wm1, *Wm2;
    const float *bQ, *bK, *bV; char* QKV; int M, b0, NB;
    if ((int)blockIdx.x < NBP) {
        A = Xp; M = Np; b0 = blockIdx.x; NB = NBP;
        Wm0 = W16 + 0 * 16384; Wm1 = W16 + 5 * 16384; Wm2 = W16 + 6 * 16384;
        bQ = bq_p; bK = bk_p; bV = bv_p; QKV = QKVp;
    } else {
        A = Xl; M = Nl; b0 = blockIdx.x - NBP; NB = NBL;
        Wm0 = W16 + 4 * 16384; Wm1 = W16 + 1 * 16384; Wm2 = W16 + 2 * 16384;
        bQ = bq_l; bK = bk_l; bV = bv_l; QKV = QKVl;
    }
    const int nt = (M + 15) >> 4;
    const int tstart = b0 * 8 + wv;        // wave-level striding: 8*NB waves
    const int tstep = NB * 8;

    stage_w512(Wm0, wlds, tid);
    stage_w512(Wm1, wlds + 32768, tid);
    __syncthreads();

    float bQc[8], bKc[8], bVc[8];
#pragma unroll
    for (int ni = 0; ni < 8; ++ni) {
        bQc[ni] = bQ[ni * 16 + l15];
        bKc[ni] = bK[ni * 16 + l15];
        bVc[ni] = bV[ni * 16 + l15];
    }

    // pass 1: Q (bf16) + K (fp8)
    for (int t = tstart; t < nt; t += tstep) {
        int wrow = t << 4;
        int r0 = wrow + l15; if (r0 > M - 1) r0 = M - 1;
        const float* Arow0 = A + (size_t)r0 * 128 + lg * 8;
        bf16x8 a0[4];
#pragma unroll
        for (int ks = 0; ks < 4; ++ks) a0[ks] = cvt8(Arow0 + ks * 32);

#pragma unroll
        for (int mat = 0; mat < 2; ++mat) {
            const char* wl = wlds + mat * 32768;
            f32x4 acc[8] = {};
#pragma unroll
            for (int ks = 0; ks < 4; ++ks) {
#pragma unroll
                for (int ni = 0; ni < 8; ++ni)
                    acc[ni] = __builtin_amdgcn_mfma_f32_16x16x32_bf16(
                        a0[ks], read_w(wl, l15, lg, ni, ks), acc[ni], 0, 0, 0);
            }
#pragma unroll
            for (int r = 0; r < 4; ++r) {
                int row = wrow + lg * 4 + r;
                if (row < M) {
                    float v[8];          // col 16*ni+l15 -> stored pos l15*8+ni
#pragma unroll
                    for (int ni = 0; ni < 8; ++ni)
                        v[ni] = acc[ni][r] + (mat == 0 ? bQc[ni] : bKc[ni]);
                    char* rowb = QKV + (size_t)row * 512;
                    if (mat == 0) {
                        bf16x8 o;
#pragma unroll
                        for (int ni = 0; ni < 8; ++ni) o[ni] = (__bf16)v[ni];
                        *reinterpret_cast<bf16x8*>(rowb + l15 * 16) = o;
                    } else {
                        *reinterpret_cast<u32x2*>(rowb + 256 + l15 * 8) = pack_fp8x8(v);
                    }
                }
            }
        }
    }

    __syncthreads();                 // all pass-1 reads of wlds done
    stage_w512(Wm2, wlds, tid);
    __syncthreads();

    // pass 2: V (fp8); A re-read (L3-served)
    for (int t = tstart; t < nt; t += tstep) {
        int wrow = t << 4;
        int r0 = wrow + l15; if (r0 > M - 1) r0 = M - 1;
        const float* Arow0 = A + (size_t)r0 * 128 + lg * 8;
        bf16x8 a0[4];
#pragma unroll
        for (int ks = 0; ks < 4; ++ks) a0[ks] = cvt8(Arow0 + ks * 32);

        f32x4 acc[8] = {};
#pragma unroll
        for (int ks = 0; ks < 4; ++ks) {
#pragma unroll
            for (int ni = 0; ni < 8; ++ni)
                acc[ni] = __builtin_amdgcn_mfma_f32_16x16x32_bf16(
                    a0[ks], read_w(wlds, l15, lg, ni, ks), acc[ni], 0, 0, 0);
        }
#pragma unroll
        for (int r = 0; r < 4; ++r) {
            int row = wrow + lg * 4 + r;
            if (row < M) {
                float v[8];
#pragma unroll
                for (int ni = 0; ni < 8; ++ni) v[ni] = acc[ni][r] + bVc[ni];
                *reinterpret_cast<u32x2*>(QKV + (size_t)row * 512 + 384 + l15 * 8)
                    = pack_fp8x8(v);
            }
        }
    }
}

// One 16-lane group per target node (4 nodes/wave); 2-way edge ILP unroll.
// Lane holds 8 (permuted) dims; K,V fp8; 4B edge records; clamp at 60.
__global__ __launch_bounds__(256) void attend(
    const char* __restrict__ QKVp, const char* __restrict__ QKVl,
    const unsigned* __restrict__ elist, const int* __restrict__ offs,
    __bf16* __restrict__ upd_pro, __bf16* __restrict__ upd_lig,
    int Np, int Ntot, float scale)
{
    int node = blockIdx.x * 16 + (threadIdx.x >> 4);
    if (node >= Ntot) return;
    int l = threadIdx.x & 15;
    const char* Qrow; const char* KV; __bf16* upd;
    if (node < Np) {
        Qrow = QKVp + (size_t)node * 512; KV = QKVl;
        upd = upd_pro + (size_t)node * 128;
    } else {
        int n = node - Np;
        Qrow = QKVl + (size_t)n * 512; KV = QKVp;
        upd = upd_lig + (size_t)n * 128;
    }
    bf16x8 qv = *reinterpret_cast<const bf16x8*>(Qrow + l * 16);
    float q[8];
#pragma unroll
    for (int j = 0; j < 8; ++j) q[j] = (float)qv[j];

    int beg = offs[node], end = offs[node + 1];
    float d = 0.f;
    float acc[8] = {};
    int i = beg;
    for (; i + 1 < end; i += 2) {
        unsigned rec0 = elist[i], rec1 = elist[i + 1];
        const char* row0 = KV + (size_t)(rec0 >> 8) * 512;
        const char* row1 = KV + (size_t)(rec1 >> 8) * 512;
        u32x2 kk0 = *reinterpret_cast<const u32x2*>(row0 + 256 + l * 8);
        u32x2 vp0 = *reinterpret_cast<const u32x2*>(row0 + 384 + l * 8);
        u32x2 kk1 = *reinterpret_cast<const u32x2*>(row1 + 256 + l * 8);
        u32x2 vp1 = *reinterpret_cast<const u32x2*>(row1 + 384 + l * 8);
        float kf0[8], vf0[8], kf1[8], vf1[8];
        unpack_fp8x8(kk0, kf0); unpack_fp8x8(vp0, vf0);
        unpack_fp8x8(kk1, kf1); unpack_fp8x8(vp1, vf1);
        float dot0 = 0.f, dot1 = 0.f;
#pragma unroll
        for (int j = 0; j < 8; ++j) { dot0 += q[j] * kf0[j]; dot1 += q[j] * kf1[j]; }
#pragma unroll
        for (int t = 1; t < 16; t <<= 1) {
            dot0 += __shfl_xor(dot0, t, 16);
            dot1 += __shfl_xor(dot1, t, 16);
        }
        f32x2 b0 = __builtin_amdgcn_cvt_pk_f32_fp8((int)(rec0 & 0xFFu), false);
        f32x2 b1 = __builtin_amdgcn_cvt_pk_f32_fp8((int)(rec1 & 0xFFu), false);
        float p0 = __expf(fminf(dot0 * scale + b0[0], 60.f));
        float p1 = __expf(fminf(dot1 * scale + b1[0], 60.f));
        d += p0 + p1;
#pragma unroll
        for (int j = 0; j < 8; ++j) acc[j] += p0 * vf0[j] + p1 * vf1[j];
    }
    if (i < end) {
        unsigned rec = elist[i];
        const char* row = KV + (size_t)(rec >> 8) * 512;
        u32x2 kk = *reinterpret_cast<const u32x2*>(row + 256 + l * 8);
        u32x2 vp = *reinterpret_cast<const u32x2*>(row + 384 + l * 8);
        float kf[8], vf[8];
        unpack_fp8x8(kk, kf); unpack_fp8x8(vp, vf);
        float dot = 0.f;
#pragma unroll
        for (int j = 0; j < 8; ++j) dot += q[j] * kf[j];
#pragma unroll
        for (int t = 1; t < 16; t <<= 1) dot += __shfl_xor(dot, t, 16);
        f32x2 bt = __builtin_amdgcn_cvt_pk_f32_fp8((int)(rec & 0xFFu), false);
        float p = __expf(fminf(dot * scale + bt[0], 60.f));
        d += p;
#pragma unroll
        for (int j = 0; j < 8; ++j) acc[j] += p * vf[j];
    }
    float inv = 1.f / (d + 1e-8f);
    bf16x8 o;
#pragma unroll
    for (int j = 0; j < 8; ++j) o[j] = (__bf16)(acc[j] * inv);
    *reinterpret_cast<bf16x8*>(upd + l * 8) = o;   // permuted bf16 layout
}

// C = LayerNorm(X + A @ Wo^T + b), both node sets (64-row blocks, 256 thr).
// A (upd) bf16 with k-permuted cols; Wo16's k-dim identically permuted.
__global__ __launch_bounds__(256) void gemm_ln_both(
    const __bf16* __restrict__ upd_pro, const __bf16* __restrict__ upd_lig,
    const float* __restrict__ Xp, const float* __restrict__ Xl,
    const __bf16* __restrict__ W16,
    const float* __restrict__ bo_p, const float* __restrict__ g_p, const float* __restrict__ be_p,
    const float* __restrict__ bo_l, const float* __restrict__ g_l, const float* __restrict__ be_l,
    float* __restrict__ out_pro, float* __restrict__ out_lig,
    int Np, int Nl, int nbp)
{
    __shared__ char wlds[32768];
    int bid = blockIdx.x;
    int tid = threadIdx.x;
    int lane = tid & 63, wv = tid >> 6;
    int l15 = lane & 15, lg = lane >> 4;

    const __bf16* A; const float* X; const __bf16* Wo;
    const float *b, *g, *be_; float* C; int M, wrow;
    if (bid < nbp) {
        A = upd_pro; X = Xp; Wo = W16 + 3 * 16384;
        b = bo_p; g = g_p; be_ = be_p; C = out_pro; M = Np; wrow = bid * 64 + wv * 16;
    } else {
        A = upd_lig; X = Xl; Wo = W16 + 7 * 16384;
        b = bo_l; g = g_l; be_ = be_l; C = out_lig; M = Nl; wrow = (bid - nbp) * 64 + wv * 16;
    }
    stage_w(Wo, wlds, tid);

    int r0 = wrow + l15; if (r0 > M - 1) r0 = M - 1;
    const __bf16* Arow0 = A + (size_t)r0 * 128 + lg * 8;
    bf16x8 a0[4];
#pragma unroll
    for (int ks = 0; ks < 4; ++ks)
        a0[ks] = *reinterpret_cast<const bf16x8*>(Arow0 + ks * 32);
    __syncthreads();

    f32x4 acc[8] = {};
#pragma unroll
    for (int ks = 0; ks < 4; ++ks) {
#pragma unroll
        for (int ni = 0; ni < 8; ++ni)
            acc[ni] = __builtin_amdgcn_mfma_f32_16x16x32_bf16(
                a0[ks], read_w(wlds, l15, lg, ni, ks), acc[ni], 0, 0, 0);
    }

    float bcol[8], gcol[8], becol[8];
#pragma unroll
    for (int ni = 0; ni < 8; ++ni) {
        bcol[ni]  = b[ni * 16 + l15];
        gcol[ni]  = g[ni * 16 + l15];
        becol[ni] = be_[ni * 16 + l15];
    }

#pragma unroll
    for (int r = 0; r < 4; ++r) {
        int row = wrow + lg * 4 + r;
        bool ok = row < M;
        int rowc = ok ? row : M - 1;
        float v[8];
#pragma unroll
        for (int ni = 0; ni < 8; ++ni) v[ni] = acc[ni][r] + bcol[ni];
        const float* Xr = X + (size_t)rowc * 128 + l15;
        float s1 = 0.f, s2 = 0.f;
#pragma unroll
        for (int ni = 0; ni < 8; ++ni) {
            v[ni] += Xr[ni * 16];
            s1 += v[ni]; s2 += v[ni] * v[ni];
        }
#pragma unroll
        for (int d = 1; d < 16; d <<= 1) {
            s1 += __shfl_xor(s1, d);
            s2 += __shfl_xor(s2, d);
        }
        float mu = s1 * 0.0078125f;
        float var = s2 * 0.0078125f - mu * mu;
        float rstd = rsqrtf(var + 1e-5f);
        if (ok) {
            float* Cr = C + (size_t)row * 128 + l15;
#pragma unroll
            for (int ni = 0; ni < 8; ++ni)
                Cr[ni * 16] = (v[ni] - mu) * rstd * gcol[ni] + becol[ni];
        }
    }
}

static inline int cdiv(int a, int b) { return (a + b - 1) / b; }

extern "C" void kernel_launch(void* const* d_in, const int* in_sizes, int n_in,
                              void* d_out, int out_size, void* d_ws, size_t ws_size,
                              hipStream_t stream)
{
    const float* pro_x  = (const float*)d_in[0];
    const float* lig_x  = (const float*)d_in[1];
    const int*   ei     = (const int*)d_in[2];
    const float* ea     = (const float*)d_in[3];
    const float* Wq_pro = (const float*)d_in[4];  const float* bq_pro = (const float*)d_in[5];
    const float* Wk_lig = (const float*)d_in[6];  const float* bk_lig = (const float*)d_in[7];
    const float* Wv_lig = (const float*)d_in[8];  const float* bv_lig = (const float*)d_in[9];
    const float* Wq_lig = (const float*)d_in[10]; const float* bq_lig = (const float*)d_in[11];
    const float* Wk_pro = (const float*)d_in[12]; const float* bk_pro = (const float*)d_in[13];
    const float* Wv_pro = (const float*)d_in[14]; const float* bv_pro = (const float*)d_in[15];
    const float* We     = (const float*)d_in[16];
    const float* Wo_pro = (const float*)d_in[17]; const float* bo_pro = (const float*)d_in[18];
    const float* Wo_lig = (const float*)d_in[19]; const float* bo_lig = (const float*)d_in[20];
    const float* g_pro  = (const float*)d_in[21]; const float* be_pro = (const float*)d_in[22];
    const float* g_lig  = (const float*)d_in[23]; const float* be_lig = (const float*)d_in[24];

    const int Np = in_sizes[0] / 128;
    const int Nl = in_sizes[1] / 128;
    const int E  = in_sizes[2] / 2;
    const int CE = in_sizes[3] / E;
    const int Nmax = Np > Nl ? Np : Nl;
    const int Ntot = Np + Nl;
    const int* pi = ei;
    const int* li = ei + E;

    float* out_pro = (float*)d_out;
    float* out_lig = out_pro + (size_t)Np * 128;

    float* ws = (float*)d_ws;
    size_t o = 0;
    char* QKVp = (char*)(ws + o); o += (size_t)Nmax * 128;       // [N][512B]
    char* QKVl = (char*)(ws + o); o += (size_t)Nmax * 128;
    float* bias = ws + o;   o += (size_t)E;
    unsigned* ranks = (unsigned*)(ws + o); o += (size_t)E;
    unsigned* elist = (unsigned*)(ws + o); o += 2 * (size_t)E;   // 2E x 4B
    int* counts = (int*)(ws + o); o += (size_t)Ntot + 8;
    int* offs   = (int*)(ws + o); o += (size_t)Ntot + 8;
    int* bsums  = (int*)(ws + o); o += 4096;
    __bf16* W16 = (__bf16*)(ws + o); o += 8 * 16384 / 2;         // [8][128][128] bf16
    __bf16* upd = (__bf16*)(ws + o); o += (size_t)Ntot * 64;     // permuted bf16
    __bf16* upd_pro = upd;
    __bf16* upd_lig = upd + (size_t)Np * 128;
    (void)ws_size; (void)n_in; (void)out_size;

    const float scale = 1.0f / sqrtf(128.0f);
    const int nEB = cdiv(E, 256);

    (void)hipMemsetAsync(counts, 0, (size_t)(Ntot + 8) * sizeof(int), stream);
    // W16 order: 0=Wq_pro 1=Wk_lig 2=Wv_lig 3=Wo_pro 4=Wq_lig 5=Wk_pro 6=Wv_pro 7=Wo_lig
    cvt_bias_count<<<64 + nEB, 256, 0, stream>>>(
        Wq_pro, Wk_lig, Wv_lig, Wo_pro, Wq_lig, Wk_pro, Wv_pro, Wo_lig, W16,
        ea, We, pi, li, bias, counts, ranks, Np, E, CE);

    const int nb1 = cdiv(Ntot, 256);
    scan1<<<nb1, 256, 0, stream>>>(counts, offs, bsums, Ntot);
    scan3<<<nb1, 256, 0, stream>>>(offs, bsums, Ntot, 2 * E);
    fill2<<<nEB, 256, 0, stream>>>(pi, li, bias, ranks, offs, elist, Np, E);

    const int NBP = 128, NBL = 128;   // persistent proj blocks per species
    proj3both<<<NBP + NBL, 512, 0, stream>>>(pro_x, lig_x, W16,
        bq_pro, bk_pro, bv_pro, bq_lig, bk_lig, bv_lig,
        QKVp, QKVl, Np, Nl, NBP, NBL);

    attend<<<cdiv(Ntot, 16), 256, 0, stream>>>(QKVp, QKVl, elist, offs,
        upd_pro, upd_lig, Np, Ntot, scale);

    const int nbp = cdiv(Np, 64), nbl = cdiv(Nl, 64);
    gemm_ln_both<<<nbp + nbl, 256, 0, stream>>>(upd_pro, upd_lig,
        pro_x, lig_x, W16, bo_pro, g_pro, be_pro, bo_lig, g_lig, be_lig,
        out_pro, out_lig, Np, Nl, nbp);
}

// Round 21
// 242.185 us; speedup vs baseline: 2.2083x; 1.3638x over previous
//
#include <hip/hip_runtime.h>
#include <float.h>
#include <math.h>

// ---------------------------------------------------------------------------
// EdgeGuidedCrossAttention, round 21 = R18 + fp8-weight projections.
// proj3both: W_q/W_k/W_v stored fp8, staged once (3 x 17KB LDS, stride 136
// -> structural-min bank pattern), MFMA = f32_16x16x32_fp8_fp8 with fp8 A.
// LDS reads become ds_read_b64 (half the LDS-pipe cost that bounded R18).
// attend: 2-way edge ILP. CSR atomic-free via ranks. upd bf16 k-permuted.
// Node table (512 B/row): Q bf16 [0,256) | K fp8 [256,384) | V fp8 [384,512).
// gemm_ln_both unchanged (Wo bf16, k-permuted).
// ---------------------------------------------------------------------------

typedef __bf16 bf16x8 __attribute__((ext_vector_type(8)));
typedef float  f32x4  __attribute__((ext_vector_type(4)));
typedef float  f32x2  __attribute__((ext_vector_type(2)));
typedef unsigned int u32x2 __attribute__((ext_vector_type(2)));

__device__ __forceinline__ bf16x8 cvt8(const float* p) {
    f32x4 lo = *reinterpret_cast<const f32x4*>(p);
    f32x4 hi = *reinterpret_cast<const f32x4*>(p + 4);
    bf16x8 r;
    r[0] = (__bf16)lo[0]; r[1] = (__bf16)lo[1]; r[2] = (__bf16)lo[2]; r[3] = (__bf16)lo[3];
    r[4] = (__bf16)hi[0]; r[5] = (__bf16)hi[1]; r[6] = (__bf16)hi[2]; r[7] = (__bf16)hi[3];
    return r;
}

__device__ __forceinline__ u32x2 pack_fp8x8(const float* v) {
    int w0 = __builtin_amdgcn_cvt_pk_fp8_f32(v[0], v[1], 0, false);
    w0 = __builtin_amdgcn_cvt_pk_fp8_f32(v[2], v[3], w0, true);
    int w1 = __builtin_amdgcn_cvt_pk_fp8_f32(v[4], v[5], 0, false);
    w1 = __builtin_amdgcn_cvt_pk_fp8_f32(v[6], v[7], w1, true);
    u32x2 r; r[0] = (unsigned)w0; r[1] = (unsigned)w1;
    return r;
}

__device__ __forceinline__ void unpack_fp8x8(u32x2 p, float* out) {
    f32x2 t0 = __builtin_amdgcn_cvt_pk_f32_fp8((int)p[0], false);
    f32x2 t1 = __builtin_amdgcn_cvt_pk_f32_fp8((int)p[0], true);
    f32x2 t2 = __builtin_amdgcn_cvt_pk_f32_fp8((int)p[1], false);
    f32x2 t3 = __builtin_amdgcn_cvt_pk_f32_fp8((int)p[1], true);
    out[0] = t0[0]; out[1] = t0[1]; out[2] = t1[0]; out[3] = t1[1];
    out[4] = t2[0]; out[5] = t2[1]; out[6] = t3[0]; out[7] = t3[1];
}

__device__ __forceinline__ long pack_fp8x8_l(const float* v) {
    return __builtin_bit_cast(long, pack_fp8x8(v));
}

// Stage one [128][128] bf16 matrix into LDS with byte ^= ((row&7)<<4) swizzle.
__device__ __forceinline__ void stage_w(const __bf16* __restrict__ Ws, char* wlds, int tid) {
#pragma unroll
    for (int it = 0; it < 8; ++it) {
        int idx = it * 2048 + tid * 8;
        int byteoff = idx * 2;
        int row = byteoff >> 8;
        *reinterpret_cast<bf16x8*>(wlds + (byteoff ^ ((row & 7) << 4)))
            = *reinterpret_cast<const bf16x8*>(Ws + idx);
    }
}
__device__ __forceinline__ bf16x8 read_w(const char* wlds, int l15, int lg, int ni, int ks) {
    int row = ni * 16 + l15;
    int off = (row * 256 + ks * 64 + lg * 16) ^ ((row & 7) << 4);
    return *reinterpret_cast<const bf16x8*>(wlds + off);
}

// Stage one [128][128] fp8 matrix into LDS with row stride 136 B.
__device__ __forceinline__ void stage_w8(const unsigned char* __restrict__ W8m, char* dst, int tid) {
#pragma unroll
    for (int it = 0; it < 8; ++it) {
        int idx = it * 2048 + tid * 8;
        int row = idx >> 7, col = idx & 127;
        *reinterpret_cast<u32x2*>(dst + row * 136 + col)
            = *reinterpret_cast<const u32x2*>(W8m + idx);
    }
}
__device__ __forceinline__ long read_w8(const char* base, int l15, int lg, int ni, int ks) {
    int off = (ni * 16 + l15) * 136 + ks * 32 + lg * 8;
    return *reinterpret_cast<const long*>(base + off);
}

// Fused front kernel:
//   blocks [0,48): 6 QKV weight mats f32 -> fp8  (W8)
//   blocks [48,64): 2 Wo mats f32 -> bf16, k-dim permuted (W16)
//   blocks [64,..): bias + counts + per-edge ranks
__global__ __launch_bounds__(256) void cvt_bias_count(
    const float* wq_p, const float* wk_p, const float* wv_p,
    const float* wq_l, const float* wk_l, const float* wv_l,
    const float* wo_p, const float* wo_l,
    unsigned char* __restrict__ W8, __bf16* __restrict__ W16,
    const float* __restrict__ ea, const float* __restrict__ We,
    const int* __restrict__ pi, const int* __restrict__ li,
    float* __restrict__ bias, int* __restrict__ counts,
    unsigned* __restrict__ ranks, int Np, int E, int CE)
{
    if (blockIdx.x < 48) {
        const float* srcs[6] = {wq_p, wk_p, wv_p, wq_l, wk_l, wv_l};
        int mat = blockIdx.x >> 3;
        int t = (blockIdx.x & 7) * 256 + threadIdx.x;
        int off = t * 8;
        float v[8];
        f32x4 lo = *reinterpret_cast<const f32x4*>(srcs[mat] + off);
        f32x4 hi = *reinterpret_cast<const f32x4*>(srcs[mat] + off + 4);
        v[0] = lo[0]; v[1] = lo[1]; v[2] = lo[2]; v[3] = lo[3];
        v[4] = hi[0]; v[5] = hi[1]; v[6] = hi[2]; v[7] = hi[3];
        *reinterpret_cast<u32x2*>(W8 + (size_t)mat * 16384 + off) = pack_fp8x8(v);
        return;
    }
    if (blockIdx.x < 64) {
        const float* srcs[2] = {wo_p, wo_l};
        int mat = (blockIdx.x - 48) >> 3;
        int t = ((blockIdx.x - 48) & 7) * 256 + threadIdx.x;
        int base = t * 8;
        const float* s = srcs[mat];
        __bf16* d = W16 + (size_t)mat * 16384;
#pragma unroll
        for (int u = 0; u < 8; ++u) {
            int idx = base + u;
            int row = idx >> 7, c = idx & 127;
            int pos = (c & 15) * 8 + (c >> 4);      // k-permuted
            d[row * 128 + pos] = (__bf16)s[idx];
        }
        return;
    }
    int e = (blockIdx.x - 64) * 256 + threadIdx.x;
    if (e >= E) return;
    const float2* row = reinterpret_cast<const float2*>(ea + (size_t)e * CE);
    float acc = 0.f;
    int h = CE >> 1;
    for (int c = 0; c < h; ++c) {
        float2 v = row[c];
        acc += v.x * We[2 * c] + v.y * We[2 * c + 1];
    }
    if (CE & 1) acc += ea[(size_t)e * CE + CE - 1] * We[CE - 1];
    bias[e] = acc;
    int r0 = atomicAdd(&counts[pi[e]], 1);
    int r1 = atomicAdd(&counts[Np + li[e]], 1);
    ranks[e] = (unsigned)(r0 & 0xFFFF) | ((unsigned)r1 << 16);
}

__global__ __launch_bounds__(256) void scan1(
    const int* __restrict__ counts, int* __restrict__ offs,
    int* __restrict__ bsums, int N)
{
    int idx = blockIdx.x * 256 + threadIdx.x;
    int v = (idx < N) ? counts[idx] : 0;
    int lane = threadIdx.x & 63, w = threadIdx.x >> 6;
    int x = v;
#pragma unroll
    for (int d = 1; d < 64; d <<= 1) {
        int y = __shfl_up(x, d);
        if (lane >= d) x += y;
    }
    __shared__ int wsum[4];
    if (lane == 63) wsum[w] = x;
    __syncthreads();
    int add = 0;
    for (int i = 0; i < w; ++i) add += wsum[i];
    x += add;
    if (idx < N) offs[idx] = x - v;
    if (threadIdx.x == 255) bsums[blockIdx.x] = x;
}

// scan3 with scan2 folded in: each block computes its prefix over raw bsums.
__global__ __launch_bounds__(256) void scan3(
    int* __restrict__ offs, const int* __restrict__ bsums, int N, int total)
{
    int b = blockIdx.x, t = threadIdx.x;
    int s = 0;
    for (int i = t; i < b; i += 256) s += bsums[i];
#pragma unroll
    for (int d = 1; d < 64; d <<= 1) s += __shfl_xor(s, d);
    __shared__ int ws_[4];
    if ((t & 63) == 0) ws_[t >> 6] = s;
    __syncthreads();
    int pre = ws_[0] + ws_[1] + ws_[2] + ws_[3];
    int idx = b * 256 + t;
    if (idx < N) offs[idx] += pre;
    if (idx == 0) offs[N] = total;
}

// Atomic-free fill: position = offs[seg] + precomputed rank. 4B records
// {other:24b | bias fp8:8b}.
__global__ __launch_bounds__(256) void fill2(
    const int* __restrict__ pi, const int* __restrict__ li,
    const float* __restrict__ bias, const unsigned* __restrict__ ranks,
    const int* __restrict__ offs, unsigned* __restrict__ elist, int Np, int E)
{
    int e = blockIdx.x * 256 + threadIdx.x;
    if (e >= E) return;
    int p = pi[e], l = li[e];
    unsigned rk = ranks[e];
    int w = __builtin_amdgcn_cvt_pk_fp8_f32(bias[e], 0.f, 0, false);
    unsigned b8 = (unsigned)w & 0xFFu;
    elist[offs[p] + (rk & 0xFFFFu)]  = ((unsigned)l << 8) | b8;
    elist[offs[Np + l] + (rk >> 16)] = ((unsigned)p << 8) | b8;
}

// Fused QKV projection, fp8 weights + fp8 A via mfma_f32_16x16x32_fp8_fp8.
// Block = 64 rows (4 waves x 16 rows); all 3 W mats staged ONCE (51 KB LDS,
// stride-136 rows -> structural-min bank pattern, ds_read_b64 fragments).
__global__ __launch_bounds__(256) void proj3both(
    const float* __restrict__ Xp, const float* __restrict__ Xl,
    const unsigned char* __restrict__ W8,
    const float* __restrict__ bq_p, const float* __restrict__ bk_p, const float* __restrict__ bv_p,
    const float* __restrict__ bq_l, const float* __restrict__ bk_l, const float* __restrict__ bv_l,
    char* __restrict__ QKVp, char* __restrict__ QKVl,
    int Np, int Nl, int nbp)
{
    __shared__ char wlds[52224];            // 3 x 128 x 136
    int bid = blockIdx.x;
    int tid = threadIdx.x;
    int lane = tid & 63, wv = tid >> 6;
    int l15 = lane & 15, lg = lane >> 4;

    const float* A; const unsigned char* Wb8;
    const float* bsels[3]; char* QKV; int M, wrow;
    if (bid < nbp) {
        A = Xp; M = Np; wrow = bid * 64 + wv * 16;
        Wb8 = W8;                            // mats 0,1,2 = q,k,v (pro)
        bsels[0] = bq_p; bsels[1] = bk_p; bsels[2] = bv_p; QKV = QKVp;
    } else {
        A = Xl; M = Nl; wrow = (bid - nbp) * 64 + wv * 16;
        Wb8 = W8 + 3 * 16384;                // mats 3,4,5 = q,k,v (lig)
        bsels[0] = bq_l; bsels[1] = bk_l; bsels[2] = bv_l; QKV = QKVl;
    }

    // stage all 3 matrices once
    stage_w8(Wb8 + 0 * 16384, wlds + 0 * 17408, tid);
    stage_w8(Wb8 + 1 * 16384, wlds + 1 * 17408, tid);
    stage_w8(Wb8 + 2 * 16384, wlds + 2 * 17408, tid);

    int r0 = wrow + l15; if (r0 > M - 1) r0 = M - 1;
    const float* Arow0 = A + (size_t)r0 * 128 + lg * 8;

    long a8[4];                              // A-frags fp8 (8 VGPR)
#pragma unroll
    for (int ks = 0; ks < 4; ++ks) {
        float v[8];
        f32x4 lo = *reinterpret_cast<const f32x4*>(Arow0 + ks * 32);
        f32x4 hi = *reinterpret_cast<const f32x4*>(Arow0 + ks * 32 + 4);
        v[0] = lo[0]; v[1] = lo[1]; v[2] = lo[2]; v[3] = lo[3];
        v[4] = hi[0]; v[5] = hi[1]; v[6] = hi[2]; v[7] = hi[3];
        a8[ks] = pack_fp8x8_l(v);
    }
    __syncthreads();

#pragma unroll
    for (int mat = 0; mat < 3; ++mat) {
        const char* wl = wlds + mat * 17408;
        f32x4 acc[8] = {};
#pragma unroll
        for (int ks = 0; ks < 4; ++ks) {
#pragma unroll
            for (int ni = 0; ni < 8; ++ni)
                acc[ni] = __builtin_amdgcn_mfma_f32_16x16x32_fp8_fp8(
                    a8[ks], read_w8(wl, l15, lg, ni, ks), acc[ni], 0, 0, 0);
        }
        float bc[8];
#pragma unroll
        for (int ni = 0; ni < 8; ++ni) bc[ni] = bsels[mat][ni * 16 + l15];
#pragma unroll
        for (int r = 0; r < 4; ++r) {
            int row = wrow + lg * 4 + r;
            if (row < M) {
                float v[8];              // col 16*ni+l15 -> stored pos l15*8+ni
#pragma unroll
                for (int ni = 0; ni < 8; ++ni) v[ni] = acc[ni][r] + bc[ni];
                char* rowb = QKV + (size_t)row * 512;
                if (mat == 0) {
                    bf16x8 o;
#pragma unroll
                    for (int ni = 0; ni < 8; ++ni) o[ni] = (__bf16)v[ni];
                    *reinterpret_cast<bf16x8*>(rowb + l15 * 16) = o;
                } else {
                    *reinterpret_cast<u32x2*>(rowb + 256 + (mat - 1) * 128 + l15 * 8)
                        = pack_fp8x8(v);
                }
            }
        }
    }
}

// One 16-lane group per target node (4 nodes/wave); 2-way edge ILP unroll.
// Lane holds 8 (permuted) dims; K,V fp8; 4B edge records; clamp at 60.
__global__ __launch_bounds__(256) void attend(
    const char* __restrict__ QKVp, const char* __restrict__ QKVl,
    const unsigned* __restrict__ elist, const int* __restrict__ offs,
    __bf16* __restrict__ upd_pro, __bf16* __restrict__ upd_lig,
    int Np, int Ntot, float scale)
{
    int node = blockIdx.x * 16 + (threadIdx.x >> 4);
    if (node >= Ntot) return;
    int l = threadIdx.x & 15;
    const char* Qrow; const char* KV; __bf16* upd;
    if (node < Np) {
        Qrow = QKVp + (size_t)node * 512; KV = QKVl;
        upd = upd_pro + (size_t)node * 128;
    } else {
        int n = node - Np;
        Qrow = QKVl + (size_t)n * 512; KV = QKVp;
        upd = upd_lig + (size_t)n * 128;
    }
    bf16x8 qv = *reinterpret_cast<const bf16x8*>(Qrow + l * 16);
    float q[8];
#pragma unroll
    for (int j = 0; j < 8; ++j) q[j] = (float)qv[j];

    int beg = offs[node], end = offs[node + 1];
    float d = 0.f;
    float acc[8] = {};
    int i = beg;
    for (; i + 1 < end; i += 2) {
        unsigned rec0 = elist[i], rec1 = elist[i + 1];
        const char* row0 = KV + (size_t)(rec0 >> 8) * 512;
        const char* row1 = KV + (size_t)(rec1 >> 8) * 512;
        u32x2 kk0 = *reinterpret_cast<const u32x2*>(row0 + 256 + l * 8);
        u32x2 vp0 = *reinterpret_cast<const u32x2*>(row0 + 384 + l * 8);
        u32x2 kk1 = *reinterpret_cast<const u32x2*>(row1 + 256 + l * 8);
        u32x2 vp1 = *reinterpret_cast<const u32x2*>(row1 + 384 + l * 8);
        float kf0[8], vf0[8], kf1[8], vf1[8];
        unpack_fp8x8(kk0, kf0); unpack_fp8x8(vp0, vf0);
        unpack_fp8x8(kk1, kf1); unpack_fp8x8(vp1, vf1);
        float dot0 = 0.f, dot1 = 0.f;
#pragma unroll
        for (int j = 0; j < 8; ++j) { dot0 += q[j] * kf0[j]; dot1 += q[j] * kf1[j]; }
#pragma unroll
        for (int t = 1; t < 16; t <<= 1) {
            dot0 += __shfl_xor(dot0, t, 16);
            dot1 += __shfl_xor(dot1, t, 16);
        }
        f32x2 b0 = __builtin_amdgcn_cvt_pk_f32_fp8((int)(rec0 & 0xFFu), false);
        f32x2 b1 = __builtin_amdgcn_cvt_pk_f32_fp8((int)(rec1 & 0xFFu), false);
        float p0 = __expf(fminf(dot0 * scale + b0[0], 60.f));
        float p1 = __expf(fminf(dot1 * scale + b1[0], 60.f));
        d += p0 + p1;
#pragma unroll
        for (int j = 0; j < 8; ++j) acc[j] += p0 * vf0[j] + p1 * vf1[j];
    }
    if (i < end) {
        unsigned rec = elist[i];
        const char* row = KV + (size_t)(rec >> 8) * 512;
        u32x2 kk = *reinterpret_cast<const u32x2*>(row + 256 + l * 8);
        u32x2 vp = *reinterpret_cast<const u32x2*>(row + 384 + l * 8);
        float kf[8], vf[8];
        unpack_fp8x8(kk, kf); unpack_fp8x8(vp, vf);
        float dot = 0.f;
#pragma unroll
        for (int j = 0; j < 8; ++j) dot += q[j] * kf[j];
#pragma unroll
        for (int t = 1; t < 16; t <<= 1) dot += __shfl_xor(dot, t, 16);
        f32x2 bt = __builtin_amdgcn_cvt_pk_f32_fp8((int)(rec & 0xFFu), false);
        float p = __expf(fminf(dot * scale + bt[0], 60.f));
        d += p;
#pragma unroll
        for (int j = 0; j < 8; ++j) acc[j] += p * vf[j];
    }
    float inv = 1.f / (d + 1e-8f);
    bf16x8 o;
#pragma unroll
    for (int j = 0; j < 8; ++j) o[j] = (__bf16)(acc[j] * inv);
    *reinterpret_cast<bf16x8*>(upd + l * 8) = o;   // permuted bf16 layout
}

// C = LayerNorm(X + A @ Wo^T + b), both node sets (64-row blocks, 256 thr).
// A (upd) bf16 with k-permuted cols; Wo16's k-dim identically permuted.
__global__ __launch_bounds__(256) void gemm_ln_both(
    const __bf16* __restrict__ upd_pro, const __bf16* __restrict__ upd_lig,
    const float* __restrict__ Xp, const float* __restrict__ Xl,
    const __bf16* __restrict__ W16,
    const float* __restrict__ bo_p, const float* __restrict__ g_p, const float* __restrict__ be_p,
    const float* __restrict__ bo_l, const float* __restrict__ g_l, const float* __restrict__ be_l,
    float* __restrict__ out_pro, float* __restrict__ out_lig,
    int Np, int Nl, int nbp)
{
    __shared__ char wlds[32768];
    int bid = blockIdx.x;
    int tid = threadIdx.x;
    int lane = tid & 63, wv = tid >> 6;
    int l15 = lane & 15, lg = lane >> 4;

    const __bf16* A; const float* X; const __bf16* Wo;
    const float *b, *g, *be_; float* C; int M, wrow;
    if (bid < nbp) {
        A = upd_pro; X = Xp; Wo = W16;
        b = bo_p; g = g_p; be_ = be_p; C = out_pro; M = Np; wrow = bid * 64 + wv * 16;
    } else {
        A = upd_lig; X = Xl; Wo = W16 + 16384;
        b = bo_l; g = g_l; be_ = be_l; C = out_lig; M = Nl; wrow = (bid - nbp) * 64 + wv * 16;
    }
    stage_w(Wo, wlds, tid);

    int r0 = wrow + l15; if (r0 > M - 1) r0 = M - 1;
    const __bf16* Arow0 = A + (size_t)r0 * 128 + lg * 8;
    bf16x8 a0[4];
#pragma unroll
    for (int ks = 0; ks < 4; ++ks)
        a0[ks] = *reinterpret_cast<const bf16x8*>(Arow0 + ks * 32);
    __syncthreads();

    f32x4 acc[8] = {};
#pragma unroll
    for (int ks = 0; ks < 4; ++ks) {
#pragma unroll
        for (int ni = 0; ni < 8; ++ni)
            acc[ni] = __builtin_amdgcn_mfma_f32_16x16x32_bf16(
                a0[ks], read_w(wlds, l15, lg, ni, ks), acc[ni], 0, 0, 0);
    }

    float bcol[8], gcol[8], becol[8];
#pragma unroll
    for (int ni = 0; ni < 8; ++ni) {
        bcol[ni]  = b[ni * 16 + l15];
        gcol[ni]  = g[ni * 16 + l15];
        becol[ni] = be_[ni * 16 + l15];
    }

#pragma unroll
    for (int r = 0; r < 4; ++r) {
        int row = wrow + lg * 4 + r;
        bool ok = row < M;
        int rowc = ok ? row : M - 1;
        float v[8];
#pragma unroll
        for (int ni = 0; ni < 8; ++ni) v[ni] = acc[ni][r] + bcol[ni];
        const float* Xr = X + (size_t)rowc * 128 + l15;
        float s1 = 0.f, s2 = 0.f;
#pragma unroll
        for (int ni = 0; ni < 8; ++ni) {
            v[ni] += Xr[ni * 16];
            s1 += v[ni]; s2 += v[ni] * v[ni];
        }
#pragma unroll
        for (int d = 1; d < 16; d <<= 1) {
            s1 += __shfl_xor(s1, d);
            s2 += __shfl_xor(s2, d);
        }
        float mu = s1 * 0.0078125f;
        float var = s2 * 0.0078125f - mu * mu;
        float rstd = rsqrtf(var + 1e-5f);
        if (ok) {
            float* Cr = C + (size_t)row * 128 + l15;
#pragma unroll
            for (int ni = 0; ni < 8; ++ni)
                Cr[ni * 16] = (v[ni] - mu) * rstd * gcol[ni] + becol[ni];
        }
    }
}

static inline int cdiv(int a, int b) { return (a + b - 1) / b; }

extern "C" void kernel_launch(void* const* d_in, const int* in_sizes, int n_in,
                              void* d_out, int out_size, void* d_ws, size_t ws_size,
                              hipStream_t stream)
{
    const float* pro_x  = (const float*)d_in[0];
    const float* lig_x  = (const float*)d_in[1];
    const int*   ei     = (const int*)d_in[2];
    const float* ea     = (const float*)d_in[3];
    const float* Wq_pro = (const float*)d_in[4];  const float* bq_pro = (const float*)d_in[5];
    const float* Wk_lig = (const float*)d_in[6];  const float* bk_lig = (const float*)d_in[7];
    const float* Wv_lig = (const float*)d_in[8];  const float* bv_lig = (const float*)d_in[9];
    const float* Wq_lig = (const float*)d_in[10]; const float* bq_lig = (const float*)d_in[11];
    const float* Wk_pro = (const float*)d_in[12]; const float* bk_pro = (const float*)d_in[13];
    const float* Wv_pro = (const float*)d_in[14]; const float* bv_pro = (const float*)d_in[15];
    const float* We     = (const float*)d_in[16];
    const float* Wo_pro = (const float*)d_in[17]; const float* bo_pro = (const float*)d_in[18];
    const float* Wo_lig = (const float*)d_in[19]; const float* bo_lig = (const float*)d_in[20];
    const float* g_pro  = (const float*)d_in[21]; const float* be_pro = (const float*)d_in[22];
    const float* g_lig  = (const float*)d_in[23]; const float* be_lig = (const float*)d_in[24];

    const int Np = in_sizes[0] / 128;
    const int Nl = in_sizes[1] / 128;
    const int E  = in_sizes[2] / 2;
    const int CE = in_sizes[3] / E;
    const int Nmax = Np > Nl ? Np : Nl;
    const int Ntot = Np + Nl;
    const int* pi = ei;
    const int* li = ei + E;

    float* out_pro = (float*)d_out;
    float* out_lig = out_pro + (size_t)Np * 128;

    float* ws = (float*)d_ws;
    size_t o = 0;
    char* QKVp = (char*)(ws + o); o += (size_t)Nmax * 128;       // [N][512B]
    char* QKVl = (char*)(ws + o); o += (size_t)Nmax * 128;
    float* bias = ws + o;   o += (size_t)E;
    unsigned* ranks = (unsigned*)(ws + o); o += (size_t)E;
    unsigned* elist = (unsigned*)(ws + o); o += 2 * (size_t)E;   // 2E x 4B
    int* counts = (int*)(ws + o); o += (size_t)Ntot + 8;
    int* offs   = (int*)(ws + o); o += (size_t)Ntot + 8;
    int* bsums  = (int*)(ws + o); o += 4096;
    unsigned char* W8 = (unsigned char*)(ws + o); o += 6 * 16384 / 4;  // [6][128][128] fp8
    __bf16* W16 = (__bf16*)(ws + o); o += 2 * 16384 / 2;         // [2][128][128] bf16 (Wo)
    __bf16* upd = (__bf16*)(ws + o); o += (size_t)Ntot * 64;     // permuted bf16
    __bf16* upd_pro = upd;
    __bf16* upd_lig = upd + (size_t)Np * 128;
    (void)ws_size; (void)n_in; (void)out_size;

    const float scale = 1.0f / sqrtf(128.0f);
    const int nEB = cdiv(E, 256);

    (void)hipMemsetAsync(counts, 0, (size_t)(Ntot + 8) * sizeof(int), stream);
    // W8 order: 0=Wq_pro 1=Wk_pro 2=Wv_pro 3=Wq_lig 4=Wk_lig 5=Wv_lig
    cvt_bias_count<<<64 + nEB, 256, 0, stream>>>(
        Wq_pro, Wk_pro, Wv_pro, Wq_lig, Wk_lig, Wv_lig, Wo_pro, Wo_lig,
        W8, W16, ea, We, pi, li, bias, counts, ranks, Np, E, CE);

    const int nb1 = cdiv(Ntot, 256);
    scan1<<<nb1, 256, 0, stream>>>(counts, offs, bsums, Ntot);
    scan3<<<nb1, 256, 0, stream>>>(offs, bsums, Ntot, 2 * E);
    fill2<<<nEB, 256, 0, stream>>>(pi, li, bias, ranks, offs, elist, Np, E);

    const int nbp = cdiv(Np, 64), nbl = cdiv(Nl, 64);
    proj3both<<<nbp + nbl, 256, 0, stream>>>(pro_x, lig_x, W8,
        bq_pro, bk_pro, bv_pro, bq_lig, bk_lig, bv_lig,
        QKVp, QKVl, Np, Nl, nbp);

    attend<<<cdiv(Ntot, 16), 256, 0, stream>>>(QKVp, QKVl, elist, offs,
        upd_pro, upd_lig, Np, Ntot, scale);

    gemm_ln_both<<<nbp + nbl, 256, 0, stream>>>(upd_pro, upd_lig,
        pro_x, lig_x, W16, bo_pro, g_pro, be_pro, bo_lig, g_lig, be_lig,
        out_pro, out_lig, Np, Nl, nbp);
}

// Round 22
// 235.584 us; speedup vs baseline: 2.2702x; 1.0280x over previous
//
#include <hip/hip_runtime.h>
#include <float.h>
#include <math.h>

// ---------------------------------------------------------------------------
// EdgeGuidedCrossAttention, round 22 = R21 + (a) bias_count 4 edges/thread
// (4x outstanding-atomic MLP; the 63us cvt_bias_count was atomic-latency
// bound at VALUBusy 1%), (b) proj3both 32 rows/wave (each ds_read_b64 W-frag
// feeds 2 MFMAs -> half the LDS-pipe ops that bound R21's proj).
// fp8-weight projections (mfma fp8_fp8, stride-136 LDS, 0 bank conflicts);
// attend 2-way ILP; CSR atomic-free via ranks; upd bf16 k-permuted.
// Node table (512 B/row): Q bf16 [0,256) | K fp8 [256,384) | V fp8 [384,512).
// ---------------------------------------------------------------------------

typedef __bf16 bf16x8 __attribute__((ext_vector_type(8)));
typedef float  f32x4  __attribute__((ext_vector_type(4)));
typedef float  f32x2  __attribute__((ext_vector_type(2)));
typedef unsigned int u32x2 __attribute__((ext_vector_type(2)));

__device__ __forceinline__ bf16x8 cvt8(const float* p) {
    f32x4 lo = *reinterpret_cast<const f32x4*>(p);
    f32x4 hi = *reinterpret_cast<const f32x4*>(p + 4);
    bf16x8 r;
    r[0] = (__bf16)lo[0]; r[1] = (__bf16)lo[1]; r[2] = (__bf16)lo[2]; r[3] = (__bf16)lo[3];
    r[4] = (__bf16)hi[0]; r[5] = (__bf16)hi[1]; r[6] = (__bf16)hi[2]; r[7] = (__bf16)hi[3];
    return r;
}

__device__ __forceinline__ u32x2 pack_fp8x8(const float* v) {
    int w0 = __builtin_amdgcn_cvt_pk_fp8_f32(v[0], v[1], 0, false);
    w0 = __builtin_amdgcn_cvt_pk_fp8_f32(v[2], v[3], w0, true);
    int w1 = __builtin_amdgcn_cvt_pk_fp8_f32(v[4], v[5], 0, false);
    w1 = __builtin_amdgcn_cvt_pk_fp8_f32(v[6], v[7], w1, true);
    u32x2 r; r[0] = (unsigned)w0; r[1] = (unsigned)w1;
    return r;
}

__device__ __forceinline__ void unpack_fp8x8(u32x2 p, float* out) {
    f32x2 t0 = __builtin_amdgcn_cvt_pk_f32_fp8((int)p[0], false);
    f32x2 t1 = __builtin_amdgcn_cvt_pk_f32_fp8((int)p[0], true);
    f32x2 t2 = __builtin_amdgcn_cvt_pk_f32_fp8((int)p[1], false);
    f32x2 t3 = __builtin_amdgcn_cvt_pk_f32_fp8((int)p[1], true);
    out[0] = t0[0]; out[1] = t0[1]; out[2] = t1[0]; out[3] = t1[1];
    out[4] = t2[0]; out[5] = t2[1]; out[6] = t3[0]; out[7] = t3[1];
}

__device__ __forceinline__ long pack_fp8x8_l(const float* v) {
    return __builtin_bit_cast(long, pack_fp8x8(v));
}

// Stage one [128][128] bf16 matrix into LDS with byte ^= ((row&7)<<4) swizzle.
__device__ __forceinline__ void stage_w(const __bf16* __restrict__ Ws, char* wlds, int tid) {
#pragma unroll
    for (int it = 0; it < 8; ++it) {
        int idx = it * 2048 + tid * 8;
        int byteoff = idx * 2;
        int row = byteoff >> 8;
        *reinterpret_cast<bf16x8*>(wlds + (byteoff ^ ((row & 7) << 4)))
            = *reinterpret_cast<const bf16x8*>(Ws + idx);
    }
}
__device__ __forceinline__ bf16x8 read_w(const char* wlds, int l15, int lg, int ni, int ks) {
    int row = ni * 16 + l15;
    int off = (row * 256 + ks * 64 + lg * 16) ^ ((row & 7) << 4);
    return *reinterpret_cast<const bf16x8*>(wlds + off);
}

// Stage one [128][128] fp8 matrix into LDS with row stride 136 B.
__device__ __forceinline__ void stage_w8(const unsigned char* __restrict__ W8m, char* dst, int tid) {
#pragma unroll
    for (int it = 0; it < 8; ++it) {
        int idx = it * 2048 + tid * 8;
        int row = idx >> 7, col = idx & 127;
        *reinterpret_cast<u32x2*>(dst + row * 136 + col)
            = *reinterpret_cast<const u32x2*>(W8m + idx);
    }
}
__device__ __forceinline__ long read_w8(const char* base, int l15, int lg, int ni, int ks) {
    int off = (ni * 16 + l15) * 136 + ks * 32 + lg * 8;
    return *reinterpret_cast<const long*>(base + off);
}

// Fused front kernel:
//   blocks [0,48): 6 QKV weight mats f32 -> fp8  (W8)
//   blocks [48,64): 2 Wo mats f32 -> bf16, k-dim permuted (W16)
//   blocks [64,..): bias + counts + ranks, 4 edges/thread (atomic MLP)
__global__ __launch_bounds__(256) void cvt_bias_count(
    const float* wq_p, const float* wk_p, const float* wv_p,
    const float* wq_l, const float* wk_l, const float* wv_l,
    const float* wo_p, const float* wo_l,
    unsigned char* __restrict__ W8, __bf16* __restrict__ W16,
    const float* __restrict__ ea, const float* __restrict__ We,
    const int* __restrict__ pi, const int* __restrict__ li,
    float* __restrict__ bias, int* __restrict__ counts,
    unsigned* __restrict__ ranks, int Np, int E, int CE)
{
    if (blockIdx.x < 48) {
        const float* srcs[6] = {wq_p, wk_p, wv_p, wq_l, wk_l, wv_l};
        int mat = blockIdx.x >> 3;
        int t = (blockIdx.x & 7) * 256 + threadIdx.x;
        int off = t * 8;
        float v[8];
        f32x4 lo = *reinterpret_cast<const f32x4*>(srcs[mat] + off);
        f32x4 hi = *reinterpret_cast<const f32x4*>(srcs[mat] + off + 4);
        v[0] = lo[0]; v[1] = lo[1]; v[2] = lo[2]; v[3] = lo[3];
        v[4] = hi[0]; v[5] = hi[1]; v[6] = hi[2]; v[7] = hi[3];
        *reinterpret_cast<u32x2*>(W8 + (size_t)mat * 16384 + off) = pack_fp8x8(v);
        return;
    }
    if (blockIdx.x < 64) {
        const float* srcs[2] = {wo_p, wo_l};
        int mat = (blockIdx.x - 48) >> 3;
        int t = ((blockIdx.x - 48) & 7) * 256 + threadIdx.x;
        int base = t * 8;
        const float* s = srcs[mat];
        __bf16* d = W16 + (size_t)mat * 16384;
#pragma unroll
        for (int u = 0; u < 8; ++u) {
            int idx = base + u;
            int row = idx >> 7, c = idx & 127;
            int pos = (c & 15) * 8 + (c >> 4);      // k-permuted
            d[row * 128 + pos] = (__bf16)s[idx];
        }
        return;
    }
    // 4 edges per thread: e, e+256, e+512, e+768 within a 1024-edge block.
    int ebase = (blockIdx.x - 64) * 1024 + threadIdx.x;
    int ev[4]; int pv[4], lv[4]; float bv[4]; int r0v[4], r1v[4]; bool ok[4];
#pragma unroll
    for (int u = 0; u < 4; ++u) {
        int e = ebase + u * 256;
        ev[u] = e; ok[u] = e < E;
        if (ok[u]) { pv[u] = pi[e]; lv[u] = li[e]; }
    }
#pragma unroll
    for (int u = 0; u < 4; ++u) {
        if (ok[u]) {
            const float2* row = reinterpret_cast<const float2*>(ea + (size_t)ev[u] * CE);
            float acc = 0.f;
            int h = CE >> 1;
            for (int c = 0; c < h; ++c) {
                float2 v = row[c];
                acc += v.x * We[2 * c] + v.y * We[2 * c + 1];
            }
            if (CE & 1) acc += ea[(size_t)ev[u] * CE + CE - 1] * We[CE - 1];
            bv[u] = acc;
        }
    }
#pragma unroll
    for (int u = 0; u < 4; ++u)
        if (ok[u]) r0v[u] = atomicAdd(&counts[pv[u]], 1);
#pragma unroll
    for (int u = 0; u < 4; ++u)
        if (ok[u]) r1v[u] = atomicAdd(&counts[Np + lv[u]], 1);
#pragma unroll
    for (int u = 0; u < 4; ++u) {
        if (ok[u]) {
            bias[ev[u]] = bv[u];
            ranks[ev[u]] = (unsigned)(r0v[u] & 0xFFFF) | ((unsigned)r1v[u] << 16);
        }
    }
}

__global__ __launch_bounds__(256) void scan1(
    const int* __restrict__ counts, int* __restrict__ offs,
    int* __restrict__ bsums, int N)
{
    int idx = blockIdx.x * 256 + threadIdx.x;
    int v = (idx < N) ? counts[idx] : 0;
    int lane = threadIdx.x & 63, w = threadIdx.x >> 6;
    int x = v;
#pragma unroll
    for (int d = 1; d < 64; d <<= 1) {
        int y = __shfl_up(x, d);
        if (lane >= d) x += y;
    }
    __shared__ int wsum[4];
    if (lane == 63) wsum[w] = x;
    __syncthreads();
    int add = 0;
    for (int i = 0; i < w; ++i) add += wsum[i];
    x += add;
    if (idx < N) offs[idx] = x - v;
    if (threadIdx.x == 255) bsums[blockIdx.x] = x;
}

// scan3 with scan2 folded in: each block computes its prefix over raw bsums.
__global__ __launch_bounds__(256) void scan3(
    int* __restrict__ offs, const int* __restrict__ bsums, int N, int total)
{
    int b = blockIdx.x, t = threadIdx.x;
    int s = 0;
    for (int i = t; i < b; i += 256) s += bsums[i];
#pragma unroll
    for (int d = 1; d < 64; d <<= 1) s += __shfl_xor(s, d);
    __shared__ int ws_[4];
    if ((t & 63) == 0) ws_[t >> 6] = s;
    __syncthreads();
    int pre = ws_[0] + ws_[1] + ws_[2] + ws_[3];
    int idx = b * 256 + t;
    if (idx < N) offs[idx] += pre;
    if (idx == 0) offs[N] = total;
}

// Atomic-free fill: position = offs[seg] + precomputed rank. 4B records
// {other:24b | bias fp8:8b}.
__global__ __launch_bounds__(256) void fill2(
    const int* __restrict__ pi, const int* __restrict__ li,
    const float* __restrict__ bias, const unsigned* __restrict__ ranks,
    const int* __restrict__ offs, unsigned* __restrict__ elist, int Np, int E)
{
    int e = blockIdx.x * 256 + threadIdx.x;
    if (e >= E) return;
    int p = pi[e], l = li[e];
    unsigned rk = ranks[e];
    int w = __builtin_amdgcn_cvt_pk_fp8_f32(bias[e], 0.f, 0, false);
    unsigned b8 = (unsigned)w & 0xFFu;
    elist[offs[p] + (rk & 0xFFFFu)]  = ((unsigned)l << 8) | b8;
    elist[offs[Np + l] + (rk >> 16)] = ((unsigned)p << 8) | b8;
}

// Fused QKV projection, fp8 weights + fp8 A via mfma_f32_16x16x32_fp8_fp8.
// Block = 128 rows (4 waves x 32 rows); all 3 W mats staged ONCE (51 KB);
// each ds_read_b64 W-frag feeds 2 MFMAs.
__global__ __launch_bounds__(256) void proj3both(
    const float* __restrict__ Xp, const float* __restrict__ Xl,
    const unsigned char* __restrict__ W8,
    const float* __restrict__ bq_p, const float* __restrict__ bk_p, const float* __restrict__ bv_p,
    const float* __restrict__ bq_l, const float* __restrict__ bk_l, const float* __restrict__ bv_l,
    char* __restrict__ QKVp, char* __restrict__ QKVl,
    int Np, int Nl, int nbp)
{
    __shared__ char wlds[52224];            // 3 x 128 x 136
    int bid = blockIdx.x;
    int tid = threadIdx.x;
    int lane = tid & 63, wv = tid >> 6;
    int l15 = lane & 15, lg = lane >> 4;

    const float* A; const unsigned char* Wb8;
    const float* bsels[3]; char* QKV; int M, wrow;
    if (bid < nbp) {
        A = Xp; M = Np; wrow = bid * 128 + wv * 32;
        Wb8 = W8;                            // mats 0,1,2 = q,k,v (pro)
        bsels[0] = bq_p; bsels[1] = bk_p; bsels[2] = bv_p; QKV = QKVp;
    } else {
        A = Xl; M = Nl; wrow = (bid - nbp) * 128 + wv * 32;
        Wb8 = W8 + 3 * 16384;                // mats 3,4,5 = q,k,v (lig)
        bsels[0] = bq_l; bsels[1] = bk_l; bsels[2] = bv_l; QKV = QKVl;
    }

    // stage all 3 matrices once
    stage_w8(Wb8 + 0 * 16384, wlds + 0 * 17408, tid);
    stage_w8(Wb8 + 1 * 16384, wlds + 1 * 17408, tid);
    stage_w8(Wb8 + 2 * 16384, wlds + 2 * 17408, tid);

    int r0 = wrow + l15;      if (r0 > M - 1) r0 = M - 1;
    int r1 = wrow + 16 + l15; if (r1 > M - 1) r1 = M - 1;
    const float* Arow0 = A + (size_t)r0 * 128 + lg * 8;
    const float* Arow1 = A + (size_t)r1 * 128 + lg * 8;

    long a8[2][4];                           // A-frags fp8 (16 VGPR)
#pragma unroll
    for (int ks = 0; ks < 4; ++ks) {
        float v[8];
        f32x4 lo = *reinterpret_cast<const f32x4*>(Arow0 + ks * 32);
        f32x4 hi = *reinterpret_cast<const f32x4*>(Arow0 + ks * 32 + 4);
        v[0] = lo[0]; v[1] = lo[1]; v[2] = lo[2]; v[3] = lo[3];
        v[4] = hi[0]; v[5] = hi[1]; v[6] = hi[2]; v[7] = hi[3];
        a8[0][ks] = pack_fp8x8_l(v);
        lo = *reinterpret_cast<const f32x4*>(Arow1 + ks * 32);
        hi = *reinterpret_cast<const f32x4*>(Arow1 + ks * 32 + 4);
        v[0] = lo[0]; v[1] = lo[1]; v[2] = lo[2]; v[3] = lo[3];
        v[4] = hi[0]; v[5] = hi[1]; v[6] = hi[2]; v[7] = hi[3];
        a8[1][ks] = pack_fp8x8_l(v);
    }
    __syncthreads();

#pragma unroll
    for (int mat = 0; mat < 3; ++mat) {
        const char* wl = wlds + mat * 17408;
        f32x4 acc[2][8] = {};
#pragma unroll
        for (int ks = 0; ks < 4; ++ks) {
#pragma unroll
            for (int ni = 0; ni < 8; ++ni) {
                long w = read_w8(wl, l15, lg, ni, ks);   // feeds 2 MFMAs
                acc[0][ni] = __builtin_amdgcn_mfma_f32_16x16x32_fp8_fp8(a8[0][ks], w, acc[0][ni], 0, 0, 0);
                acc[1][ni] = __builtin_amdgcn_mfma_f32_16x16x32_fp8_fp8(a8[1][ks], w, acc[1][ni], 0, 0, 0);
            }
        }
        float bc[8];
#pragma unroll
        for (int ni = 0; ni < 8; ++ni) bc[ni] = bsels[mat][ni * 16 + l15];
#pragma unroll
        for (int mi = 0; mi < 2; ++mi) {
#pragma unroll
            for (int r = 0; r < 4; ++r) {
                int row = wrow + mi * 16 + lg * 4 + r;
                if (row < M) {
                    float v[8];          // col 16*ni+l15 -> stored pos l15*8+ni
#pragma unroll
                    for (int ni = 0; ni < 8; ++ni) v[ni] = acc[mi][ni][r] + bc[ni];
                    char* rowb = QKV + (size_t)row * 512;
                    if (mat == 0) {
                        bf16x8 o;
#pragma unroll
                        for (int ni = 0; ni < 8; ++ni) o[ni] = (__bf16)v[ni];
                        *reinterpret_cast<bf16x8*>(rowb + l15 * 16) = o;
                    } else {
                        *reinterpret_cast<u32x2*>(rowb + 256 + (mat - 1) * 128 + l15 * 8)
                            = pack_fp8x8(v);
                    }
                }
            }
        }
    }
}

// One 16-lane group per target node (4 nodes/wave); 2-way edge ILP unroll.
// Lane holds 8 (permuted) dims; K,V fp8; 4B edge records; clamp at 60.
__global__ __launch_bounds__(256) void attend(
    const char* __restrict__ QKVp, const char* __restrict__ QKVl,
    const unsigned* __restrict__ elist, const int* __restrict__ offs,
    __bf16* __restrict__ upd_pro, __bf16* __restrict__ upd_lig,
    int Np, int Ntot, float scale)
{
    int node = blockIdx.x * 16 + (threadIdx.x >> 4);
    if (node >= Ntot) return;
    int l = threadIdx.x & 15;
    const char* Qrow; const char* KV; __bf16* upd;
    if (node < Np) {
        Qrow = QKVp + (size_t)node * 512; KV = QKVl;
        upd = upd_pro + (size_t)node * 128;
    } else {
        int n = node - Np;
        Qrow = QKVl + (size_t)n * 512; KV = QKVp;
        upd = upd_lig + (size_t)n * 128;
    }
    bf16x8 qv = *reinterpret_cast<const bf16x8*>(Qrow + l * 16);
    float q[8];
#pragma unroll
    for (int j = 0; j < 8; ++j) q[j] = (float)qv[j];

    int beg = offs[node], end = offs[node + 1];
    float d = 0.f;
    float acc[8] = {};
    int i = beg;
    for (; i + 1 < end; i += 2) {
        unsigned rec0 = elist[i], rec1 = elist[i + 1];
        const char* row0 = KV + (size_t)(rec0 >> 8) * 512;
        const char* row1 = KV + (size_t)(rec1 >> 8) * 512;
        u32x2 kk0 = *reinterpret_cast<const u32x2*>(row0 + 256 + l * 8);
        u32x2 vp0 = *reinterpret_cast<const u32x2*>(row0 + 384 + l * 8);
        u32x2 kk1 = *reinterpret_cast<const u32x2*>(row1 + 256 + l * 8);
        u32x2 vp1 = *reinterpret_cast<const u32x2*>(row1 + 384 + l * 8);
        float kf0[8], vf0[8], kf1[8], vf1[8];
        unpack_fp8x8(kk0, kf0); unpack_fp8x8(vp0, vf0);
        unpack_fp8x8(kk1, kf1); unpack_fp8x8(vp1, vf1);
        float dot0 = 0.f, dot1 = 0.f;
#pragma unroll
        for (int j = 0; j < 8; ++j) { dot0 += q[j] * kf0[j]; dot1 += q[j] * kf1[j]; }
#pragma unroll
        for (int t = 1; t < 16; t <<= 1) {
            dot0 += __shfl_xor(dot0, t, 16);
            dot1 += __shfl_xor(dot1, t, 16);
        }
        f32x2 b0 = __builtin_amdgcn_cvt_pk_f32_fp8((int)(rec0 & 0xFFu), false);
        f32x2 b1 = __builtin_amdgcn_cvt_pk_f32_fp8((int)(rec1 & 0xFFu), false);
        float p0 = __expf(fminf(dot0 * scale + b0[0], 60.f));
        float p1 = __expf(fminf(dot1 * scale + b1[0], 60.f));
        d += p0 + p1;
#pragma unroll
        for (int j = 0; j < 8; ++j) acc[j] += p0 * vf0[j] + p1 * vf1[j];
    }
    if (i < end) {
        unsigned rec = elist[i];
        const char* row = KV + (size_t)(rec >> 8) * 512;
        u32x2 kk = *reinterpret_cast<const u32x2*>(row + 256 + l * 8);
        u32x2 vp = *reinterpret_cast<const u32x2*>(row + 384 + l * 8);
        float kf[8], vf[8];
        unpack_fp8x8(kk, kf); unpack_fp8x8(vp, vf);
        float dot = 0.f;
#pragma unroll
        for (int j = 0; j < 8; ++j) dot += q[j] * kf[j];
#pragma unroll
        for (int t = 1; t < 16; t <<= 1) dot += __shfl_xor(dot, t, 16);
        f32x2 bt = __builtin_amdgcn_cvt_pk_f32_fp8((int)(rec & 0xFFu), false);
        float p = __expf(fminf(dot * scale + bt[0], 60.f));
        d += p;
#pragma unroll
        for (int j = 0; j < 8; ++j) acc[j] += p * vf[j];
    }
    float inv = 1.f / (d + 1e-8f);
    bf16x8 o;
#pragma unroll
    for (int j = 0; j < 8; ++j) o[j] = (__bf16)(acc[j] * inv);
    *reinterpret_cast<bf16x8*>(upd + l * 8) = o;   // permuted bf16 layout
}

// C = LayerNorm(X + A @ Wo^T + b), both node sets (64-row blocks, 256 thr).
// A (upd) bf16 with k-permuted cols; Wo16's k-dim identically permuted.
__global__ __launch_bounds__(256) void gemm_ln_both(
    const __bf16* __restrict__ upd_pro, const __bf16* __restrict__ upd_lig,
    const float* __restrict__ Xp, const float* __restrict__ Xl,
    const __bf16* __restrict__ W16,
    const float* __restrict__ bo_p, const float* __restrict__ g_p, const float* __restrict__ be_p,
    const float* __restrict__ bo_l, const float* __restrict__ g_l, const float* __restrict__ be_l,
    float* __restrict__ out_pro, float* __restrict__ out_lig,
    int Np, int Nl, int nbp)
{
    __shared__ char wlds[32768];
    int bid = blockIdx.x;
    int tid = threadIdx.x;
    int lane = tid & 63, wv = tid >> 6;
    int l15 = lane & 15, lg = lane >> 4;

    const __bf16* A; const float* X; const __bf16* Wo;
    const float *b, *g, *be_; float* C; int M, wrow;
    if (bid < nbp) {
        A = upd_pro; X = Xp; Wo = W16;
        b = bo_p; g = g_p; be_ = be_p; C = out_pro; M = Np; wrow = bid * 64 + wv * 16;
    } else {
        A = upd_lig; X = Xl; Wo = W16 + 16384;
        b = bo_l; g = g_l; be_ = be_l; C = out_lig; M = Nl; wrow = (bid - nbp) * 64 + wv * 16;
    }
    stage_w(Wo, wlds, tid);

    int r0 = wrow + l15; if (r0 > M - 1) r0 = M - 1;
    const __bf16* Arow0 = A + (size_t)r0 * 128 + lg * 8;
    bf16x8 a0[4];
#pragma unroll
    for (int ks = 0; ks < 4; ++ks)
        a0[ks] = *reinterpret_cast<const bf16x8*>(Arow0 + ks * 32);
    __syncthreads();

    f32x4 acc[8] = {};
#pragma unroll
    for (int ks = 0; ks < 4; ++ks) {
#pragma unroll
        for (int ni = 0; ni < 8; ++ni)
            acc[ni] = __builtin_amdgcn_mfma_f32_16x16x32_bf16(
                a0[ks], read_w(wlds, l15, lg, ni, ks), acc[ni], 0, 0, 0);
    }

    float bcol[8], gcol[8], becol[8];
#pragma unroll
    for (int ni = 0; ni < 8; ++ni) {
        bcol[ni]  = b[ni * 16 + l15];
        gcol[ni]  = g[ni * 16 + l15];
        becol[ni] = be_[ni * 16 + l15];
    }

#pragma unroll
    for (int r = 0; r < 4; ++r) {
        int row = wrow + lg * 4 + r;
        bool ok = row < M;
        int rowc = ok ? row : M - 1;
        float v[8];
#pragma unroll
        for (int ni = 0; ni < 8; ++ni) v[ni] = acc[ni][r] + bcol[ni];
        const float* Xr = X + (size_t)rowc * 128 + l15;
        float s1 = 0.f, s2 = 0.f;
#pragma unroll
        for (int ni = 0; ni < 8; ++ni) {
            v[ni] += Xr[ni * 16];
            s1 += v[ni]; s2 += v[ni] * v[ni];
        }
#pragma unroll
        for (int d = 1; d < 16; d <<= 1) {
            s1 += __shfl_xor(s1, d);
            s2 += __shfl_xor(s2, d);
        }
        float mu = s1 * 0.0078125f;
        float var = s2 * 0.0078125f - mu * mu;
        float rstd = rsqrtf(var + 1e-5f);
        if (ok) {
            float* Cr = C + (size_t)row * 128 + l15;
#pragma unroll
            for (int ni = 0; ni < 8; ++ni)
                Cr[ni * 16] = (v[ni] - mu) * rstd * gcol[ni] + becol[ni];
        }
    }
}

static inline int cdiv(int a, int b) { return (a + b - 1) / b; }

extern "C" void kernel_launch(void* const* d_in, const int* in_sizes, int n_in,
                              void* d_out, int out_size, void* d_ws, size_t ws_size,
                              hipStream_t stream)
{
    const float* pro_x  = (const float*)d_in[0];
    const float* lig_x  = (const float*)d_in[1];
    const int*   ei     = (const int*)d_in[2];
    const float* ea     = (const float*)d_in[3];
    const float* Wq_pro = (const float*)d_in[4];  const float* bq_pro = (const float*)d_in[5];
    const float* Wk_lig = (const float*)d_in[6];  const float* bk_lig = (const float*)d_in[7];
    const float* Wv_lig = (const float*)d_in[8];  const float* bv_lig = (const float*)d_in[9];
    const float* Wq_lig = (const float*)d_in[10]; const float* bq_lig = (const float*)d_in[11];
    const float* Wk_pro = (const float*)d_in[12]; const float* bk_pro = (const float*)d_in[13];
    const float* Wv_pro = (const float*)d_in[14]; const float* bv_pro = (const float*)d_in[15];
    const float* We     = (const float*)d_in[16];
    const float* Wo_pro = (const float*)d_in[17]; const float* bo_pro = (const float*)d_in[18];
    const float* Wo_lig = (const float*)d_in[19]; const float* bo_lig = (const float*)d_in[20];
    const float* g_pro  = (const float*)d_in[21]; const float* be_pro = (const float*)d_in[22];
    const float* g_lig  = (const float*)d_in[23]; const float* be_lig = (const float*)d_in[24];

    const int Np = in_sizes[0] / 128;
    const int Nl = in_sizes[1] / 128;
    const int E  = in_sizes[2] / 2;
    const int CE = in_sizes[3] / E;
    const int Nmax = Np > Nl ? Np : Nl;
    const int Ntot = Np + Nl;
    const int* pi = ei;
    const int* li = ei + E;

    float* out_pro = (float*)d_out;
    float* out_lig = out_pro + (size_t)Np * 128;

    float* ws = (float*)d_ws;
    size_t o = 0;
    char* QKVp = (char*)(ws + o); o += (size_t)Nmax * 128;       // [N][512B]
    char* QKVl = (char*)(ws + o); o += (size_t)Nmax * 128;
    float* bias = ws + o;   o += (size_t)E;
    unsigned* ranks = (unsigned*)(ws + o); o += (size_t)E;
    unsigned* elist = (unsigned*)(ws + o); o += 2 * (size_t)E;   // 2E x 4B
    int* counts = (int*)(ws + o); o += (size_t)Ntot + 8;
    int* offs   = (int*)(ws + o); o += (size_t)Ntot + 8;
    int* bsums  = (int*)(ws + o); o += 4096;
    unsigned char* W8 = (unsigned char*)(ws + o); o += 6 * 16384 / 4;  // [6][128][128] fp8
    __bf16* W16 = (__bf16*)(ws + o); o += 2 * 16384 / 2;         // [2][128][128] bf16 (Wo)
    __bf16* upd = (__bf16*)(ws + o); o += (size_t)Ntot * 64;     // permuted bf16
    __bf16* upd_pro = upd;
    __bf16* upd_lig = upd + (size_t)Np * 128;
    (void)ws_size; (void)n_in; (void)out_size;

    const float scale = 1.0f / sqrtf(128.0f);
    const int nEB = cdiv(E, 256);
    const int nEB4 = cdiv(E, 1024);

    (void)hipMemsetAsync(counts, 0, (size_t)(Ntot + 8) * sizeof(int), stream);
    // W8 order: 0=Wq_pro 1=Wk_pro 2=Wv_pro 3=Wq_lig 4=Wk_lig 5=Wv_lig
    cvt_bias_count<<<64 + nEB4, 256, 0, stream>>>(
        Wq_pro, Wk_pro, Wv_pro, Wq_lig, Wk_lig, Wv_lig, Wo_pro, Wo_lig,
        W8, W16, ea, We, pi, li, bias, counts, ranks, Np, E, CE);

    const int nb1 = cdiv(Ntot, 256);
    scan1<<<nb1, 256, 0, stream>>>(counts, offs, bsums, Ntot);
    scan3<<<nb1, 256, 0, stream>>>(offs, bsums, Ntot, 2 * E);
    fill2<<<nEB, 256, 0, stream>>>(pi, li, bias, ranks, offs, elist, Np, E);

    const int nbp = cdiv(Np, 128), nbl = cdiv(Nl, 128);
    proj3both<<<nbp + nbl, 256, 0, stream>>>(pro_x, lig_x, W8,
        bq_pro, bk_pro, bv_pro, bq_lig, bk_lig, bv_lig,
        QKVp, QKVl, Np, Nl, nbp);

    attend<<<cdiv(Ntot, 16), 256, 0, stream>>>(QKVp, QKVl, elist, offs,
        upd_pro, upd_lig, Np, Ntot, scale);

    const int nbp2 = cdiv(Np, 64), nbl2 = cdiv(Nl, 64);
    gemm_ln_both<<<nbp2 + nbl2, 256, 0, stream>>>(upd_pro, upd_lig,
        pro_x, lig_x, W16, bo_pro, g_pro, be_pro, bo_lig, g_lig, be_lig,
        out_pro, out_lig, Np, Nl, nbp2);
}

// Round 23
// 231.421 us; speedup vs baseline: 2.3110x; 1.0180x over previous
//
#include <hip/hip_runtime.h>
#include <float.h>
#include <math.h>

// ---------------------------------------------------------------------------
// EdgeGuidedCrossAttention, round 23 = R22 with:
//   (a) proj reverted to R21's 16-rows/wave shape (VGPR 68, occ 26% > R22's
//       32-row/VGPR-92 variant),
//   (b) fill2 FUSED into the proj launch (grid-split): both depend only on
//       {scan3, cvt}; fill2's ~13us of latency-bound scatter hides under proj.
// fp8-weight projections (mfma fp8_fp8, stride-136 LDS, 0 bank conflicts);
// attend 2-way ILP; CSR atomic-free via ranks; upd bf16 k-permuted.
// Node table (512 B/row): Q bf16 [0,256) | K fp8 [256,384) | V fp8 [384,512).
// ---------------------------------------------------------------------------

typedef __bf16 bf16x8 __attribute__((ext_vector_type(8)));
typedef float  f32x4  __attribute__((ext_vector_type(4)));
typedef float  f32x2  __attribute__((ext_vector_type(2)));
typedef unsigned int u32x2 __attribute__((ext_vector_type(2)));

__device__ __forceinline__ u32x2 pack_fp8x8(const float* v) {
    int w0 = __builtin_amdgcn_cvt_pk_fp8_f32(v[0], v[1], 0, false);
    w0 = __builtin_amdgcn_cvt_pk_fp8_f32(v[2], v[3], w0, true);
    int w1 = __builtin_amdgcn_cvt_pk_fp8_f32(v[4], v[5], 0, false);
    w1 = __builtin_amdgcn_cvt_pk_fp8_f32(v[6], v[7], w1, true);
    u32x2 r; r[0] = (unsigned)w0; r[1] = (unsigned)w1;
    return r;
}

__device__ __forceinline__ void unpack_fp8x8(u32x2 p, float* out) {
    f32x2 t0 = __builtin_amdgcn_cvt_pk_f32_fp8((int)p[0], false);
    f32x2 t1 = __builtin_amdgcn_cvt_pk_f32_fp8((int)p[0], true);
    f32x2 t2 = __builtin_amdgcn_cvt_pk_f32_fp8((int)p[1], false);
    f32x2 t3 = __builtin_amdgcn_cvt_pk_f32_fp8((int)p[1], true);
    out[0] = t0[0]; out[1] = t0[1]; out[2] = t1[0]; out[3] = t1[1];
    out[4] = t2[0]; out[5] = t2[1]; out[6] = t3[0]; out[7] = t3[1];
}

__device__ __forceinline__ long pack_fp8x8_l(const float* v) {
    return __builtin_bit_cast(long, pack_fp8x8(v));
}

// Stage one [128][128] bf16 matrix into LDS with byte ^= ((row&7)<<4) swizzle.
__device__ __forceinline__ void stage_w(const __bf16* __restrict__ Ws, char* wlds, int tid) {
#pragma unroll
    for (int it = 0; it < 8; ++it) {
        int idx = it * 2048 + tid * 8;
        int byteoff = idx * 2;
        int row = byteoff >> 8;
        *reinterpret_cast<bf16x8*>(wlds + (byteoff ^ ((row & 7) << 4)))
            = *reinterpret_cast<const bf16x8*>(Ws + idx);
    }
}
__device__ __forceinline__ bf16x8 read_w(const char* wlds, int l15, int lg, int ni, int ks) {
    int row = ni * 16 + l15;
    int off = (row * 256 + ks * 64 + lg * 16) ^ ((row & 7) << 4);
    return *reinterpret_cast<const bf16x8*>(wlds + off);
}

// Stage one [128][128] fp8 matrix into LDS with row stride 136 B.
__device__ __forceinline__ void stage_w8(const unsigned char* __restrict__ W8m, char* dst, int tid) {
#pragma unroll
    for (int it = 0; it < 8; ++it) {
        int idx = it * 2048 + tid * 8;
        int row = idx >> 7, col = idx & 127;
        *reinterpret_cast<u32x2*>(dst + row * 136 + col)
            = *reinterpret_cast<const u32x2*>(W8m + idx);
    }
}
__device__ __forceinline__ long read_w8(const char* base, int l15, int lg, int ni, int ks) {
    int off = (ni * 16 + l15) * 136 + ks * 32 + lg * 8;
    return *reinterpret_cast<const long*>(base + off);
}

// Fused front kernel:
//   blocks [0,48): 6 QKV weight mats f32 -> fp8  (W8)
//   blocks [48,64): 2 Wo mats f32 -> bf16, k-dim permuted (W16)
//   blocks [64,..): bias + counts + ranks, 4 edges/thread (atomic MLP)
__global__ __launch_bounds__(256) void cvt_bias_count(
    const float* wq_p, const float* wk_p, const float* wv_p,
    const float* wq_l, const float* wk_l, const float* wv_l,
    const float* wo_p, const float* wo_l,
    unsigned char* __restrict__ W8, __bf16* __restrict__ W16,
    const float* __restrict__ ea, const float* __restrict__ We,
    const int* __restrict__ pi, const int* __restrict__ li,
    float* __restrict__ bias, int* __restrict__ counts,
    unsigned* __restrict__ ranks, int Np, int E, int CE)
{
    if (blockIdx.x < 48) {
        const float* srcs[6] = {wq_p, wk_p, wv_p, wq_l, wk_l, wv_l};
        int mat = blockIdx.x >> 3;
        int t = (blockIdx.x & 7) * 256 + threadIdx.x;
        int off = t * 8;
        float v[8];
        f32x4 lo = *reinterpret_cast<const f32x4*>(srcs[mat] + off);
        f32x4 hi = *reinterpret_cast<const f32x4*>(srcs[mat] + off + 4);
        v[0] = lo[0]; v[1] = lo[1]; v[2] = lo[2]; v[3] = lo[3];
        v[4] = hi[0]; v[5] = hi[1]; v[6] = hi[2]; v[7] = hi[3];
        *reinterpret_cast<u32x2*>(W8 + (size_t)mat * 16384 + off) = pack_fp8x8(v);
        return;
    }
    if (blockIdx.x < 64) {
        const float* srcs[2] = {wo_p, wo_l};
        int mat = (blockIdx.x - 48) >> 3;
        int t = ((blockIdx.x - 48) & 7) * 256 + threadIdx.x;
        int base = t * 8;
        const float* s = srcs[mat];
        __bf16* d = W16 + (size_t)mat * 16384;
#pragma unroll
        for (int u = 0; u < 8; ++u) {
            int idx = base + u;
            int row = idx >> 7, c = idx & 127;
            int pos = (c & 15) * 8 + (c >> 4);      // k-permuted
            d[row * 128 + pos] = (__bf16)s[idx];
        }
        return;
    }
    // 4 edges per thread (atomic MLP).
    int ebase = (blockIdx.x - 64) * 1024 + threadIdx.x;
    int ev[4]; int pv[4], lv[4]; float bv[4]; int r0v[4], r1v[4]; bool ok[4];
#pragma unroll
    for (int u = 0; u < 4; ++u) {
        int e = ebase + u * 256;
        ev[u] = e; ok[u] = e < E;
        if (ok[u]) { pv[u] = pi[e]; lv[u] = li[e]; }
    }
#pragma unroll
    for (int u = 0; u < 4; ++u) {
        if (ok[u]) {
            const float2* row = reinterpret_cast<const float2*>(ea + (size_t)ev[u] * CE);
            float acc = 0.f;
            int h = CE >> 1;
            for (int c = 0; c < h; ++c) {
                float2 v = row[c];
                acc += v.x * We[2 * c] + v.y * We[2 * c + 1];
            }
            if (CE & 1) acc += ea[(size_t)ev[u] * CE + CE - 1] * We[CE - 1];
            bv[u] = acc;
        }
    }
#pragma unroll
    for (int u = 0; u < 4; ++u)
        if (ok[u]) r0v[u] = atomicAdd(&counts[pv[u]], 1);
#pragma unroll
    for (int u = 0; u < 4; ++u)
        if (ok[u]) r1v[u] = atomicAdd(&counts[Np + lv[u]], 1);
#pragma unroll
    for (int u = 0; u < 4; ++u) {
        if (ok[u]) {
            bias[ev[u]] = bv[u];
            ranks[ev[u]] = (unsigned)(r0v[u] & 0xFFFF) | ((unsigned)r1v[u] << 16);
        }
    }
}

__global__ __launch_bounds__(256) void scan1(
    const int* __restrict__ counts, int* __restrict__ offs,
    int* __restrict__ bsums, int N)
{
    int idx = blockIdx.x * 256 + threadIdx.x;
    int v = (idx < N) ? counts[idx] : 0;
    int lane = threadIdx.x & 63, w = threadIdx.x >> 6;
    int x = v;
#pragma unroll
    for (int d = 1; d < 64; d <<= 1) {
        int y = __shfl_up(x, d);
        if (lane >= d) x += y;
    }
    __shared__ int wsum[4];
    if (lane == 63) wsum[w] = x;
    __syncthreads();
    int add = 0;
    for (int i = 0; i < w; ++i) add += wsum[i];
    x += add;
    if (idx < N) offs[idx] = x - v;
    if (threadIdx.x == 255) bsums[blockIdx.x] = x;
}

// scan3 with scan2 folded in: each block computes its prefix over raw bsums.
__global__ __launch_bounds__(256) void scan3(
    int* __restrict__ offs, const int* __restrict__ bsums, int N, int total)
{
    int b = blockIdx.x, t = threadIdx.x;
    int s = 0;
    for (int i = t; i < b; i += 256) s += bsums[i];
#pragma unroll
    for (int d = 1; d < 64; d <<= 1) s += __shfl_xor(s, d);
    __shared__ int ws_[4];
    if ((t & 63) == 0) ws_[t >> 6] = s;
    __syncthreads();
    int pre = ws_[0] + ws_[1] + ws_[2] + ws_[3];
    int idx = b * 256 + t;
    if (idx < N) offs[idx] += pre;
    if (idx == 0) offs[N] = total;
}

// Fused proj + fill launch.
// Blocks [0, nbProj): fp8 QKV projection (64 rows, 4 waves x 16 rows, all 3
//   W mats staged once in 51 KB LDS, mfma fp8_fp8, 0 bank conflicts).
// Blocks [nbProj, ..): atomic-free CSR fill (4B records {other:24|bias fp8:8})
//   -- latency-bound scatter that hides under the proj blocks.
__global__ __launch_bounds__(256) void proj_fill(
    const float* __restrict__ Xp, const float* __restrict__ Xl,
    const unsigned char* __restrict__ W8,
    const float* __restrict__ bq_p, const float* __restrict__ bk_p, const float* __restrict__ bv_p,
    const float* __restrict__ bq_l, const float* __restrict__ bk_l, const float* __restrict__ bv_l,
    char* __restrict__ QKVp, char* __restrict__ QKVl,
    const int* __restrict__ pi, const int* __restrict__ li,
    const float* __restrict__ bias, const unsigned* __restrict__ ranks,
    const int* __restrict__ offs, unsigned* __restrict__ elist,
    int Np, int Nl, int nbp, int nbProj, int E)
{
    __shared__ char wlds[52224];            // 3 x 128 x 136
    int bid = blockIdx.x;
    int tid = threadIdx.x;

    if (bid >= nbProj) {                    // ---- fill2 branch ----
        int e = (bid - nbProj) * 256 + tid;
        if (e >= E) return;
        int p = pi[e], l = li[e];
        unsigned rk = ranks[e];
        int w = __builtin_amdgcn_cvt_pk_fp8_f32(bias[e], 0.f, 0, false);
        unsigned b8 = (unsigned)w & 0xFFu;
        elist[offs[p] + (rk & 0xFFFFu)]  = ((unsigned)l << 8) | b8;
        elist[offs[Np + l] + (rk >> 16)] = ((unsigned)p << 8) | b8;
        return;
    }

    // ---- proj branch ----
    int lane = tid & 63, wv = tid >> 6;
    int l15 = lane & 15, lg = lane >> 4;

    const float* A; const unsigned char* Wb8;
    const float* bsels[3]; char* QKV; int M, wrow;
    if (bid < nbp) {
        A = Xp; M = Np; wrow = bid * 64 + wv * 16;
        Wb8 = W8;                            // mats 0,1,2 = q,k,v (pro)
        bsels[0] = bq_p; bsels[1] = bk_p; bsels[2] = bv_p; QKV = QKVp;
    } else {
        A = Xl; M = Nl; wrow = (bid - nbp) * 64 + wv * 16;
        Wb8 = W8 + 3 * 16384;                // mats 3,4,5 = q,k,v (lig)
        bsels[0] = bq_l; bsels[1] = bk_l; bsels[2] = bv_l; QKV = QKVl;
    }

    stage_w8(Wb8 + 0 * 16384, wlds + 0 * 17408, tid);
    stage_w8(Wb8 + 1 * 16384, wlds + 1 * 17408, tid);
    stage_w8(Wb8 + 2 * 16384, wlds + 2 * 17408, tid);

    int r0 = wrow + l15; if (r0 > M - 1) r0 = M - 1;
    const float* Arow0 = A + (size_t)r0 * 128 + lg * 8;

    long a8[4];                              // A-frags fp8 (8 VGPR)
#pragma unroll
    for (int ks = 0; ks < 4; ++ks) {
        float v[8];
        f32x4 lo = *reinterpret_cast<const f32x4*>(Arow0 + ks * 32);
        f32x4 hi = *reinterpret_cast<const f32x4*>(Arow0 + ks * 32 + 4);
        v[0] = lo[0]; v[1] = lo[1]; v[2] = lo[2]; v[3] = lo[3];
        v[4] = hi[0]; v[5] = hi[1]; v[6] = hi[2]; v[7] = hi[3];
        a8[ks] = pack_fp8x8_l(v);
    }
    __syncthreads();

#pragma unroll
    for (int mat = 0; mat < 3; ++mat) {
        const char* wl = wlds + mat * 17408;
        f32x4 acc[8] = {};
#pragma unroll
        for (int ks = 0; ks < 4; ++ks) {
#pragma unroll
            for (int ni = 0; ni < 8; ++ni)
                acc[ni] = __builtin_amdgcn_mfma_f32_16x16x32_fp8_fp8(
                    a8[ks], read_w8(wl, l15, lg, ni, ks), acc[ni], 0, 0, 0);
        }
        float bc[8];
#pragma unroll
        for (int ni = 0; ni < 8; ++ni) bc[ni] = bsels[mat][ni * 16 + l15];
#pragma unroll
        for (int r = 0; r < 4; ++r) {
            int row = wrow + lg * 4 + r;
            if (row < M) {
                float v[8];              // col 16*ni+l15 -> stored pos l15*8+ni
#pragma unroll
                for (int ni = 0; ni < 8; ++ni) v[ni] = acc[ni][r] + bc[ni];
                char* rowb = QKV + (size_t)row * 512;
                if (mat == 0) {
                    bf16x8 o;
#pragma unroll
                    for (int ni = 0; ni < 8; ++ni) o[ni] = (__bf16)v[ni];
                    *reinterpret_cast<bf16x8*>(rowb + l15 * 16) = o;
                } else {
                    *reinterpret_cast<u32x2*>(rowb + 256 + (mat - 1) * 128 + l15 * 8)
                        = pack_fp8x8(v);
                }
            }
        }
    }
}

// One 16-lane group per target node (4 nodes/wave); 2-way edge ILP unroll.
// Lane holds 8 (permuted) dims; K,V fp8; 4B edge records; clamp at 60.
__global__ __launch_bounds__(256) void attend(
    const char* __restrict__ QKVp, const char* __restrict__ QKVl,
    const unsigned* __restrict__ elist, const int* __restrict__ offs,
    __bf16* __restrict__ upd_pro, __bf16* __restrict__ upd_lig,
    int Np, int Ntot, float scale)
{
    int node = blockIdx.x * 16 + (threadIdx.x >> 4);
    if (node >= Ntot) return;
    int l = threadIdx.x & 15;
    const char* Qrow; const char* KV; __bf16* upd;
    if (node < Np) {
        Qrow = QKVp + (size_t)node * 512; KV = QKVl;
        upd = upd_pro + (size_t)node * 128;
    } else {
        int n = node - Np;
        Qrow = QKVl + (size_t)n * 512; KV = QKVp;
        upd = upd_lig + (size_t)n * 128;
    }
    bf16x8 qv = *reinterpret_cast<const bf16x8*>(Qrow + l * 16);
    float q[8];
#pragma unroll
    for (int j = 0; j < 8; ++j) q[j] = (float)qv[j];

    int beg = offs[node], end = offs[node + 1];
    float d = 0.f;
    float acc[8] = {};
    int i = beg;
    for (; i + 1 < end; i += 2) {
        unsigned rec0 = elist[i], rec1 = elist[i + 1];
        const char* row0 = KV + (size_t)(rec0 >> 8) * 512;
        const char* row1 = KV + (size_t)(rec1 >> 8) * 512;
        u32x2 kk0 = *reinterpret_cast<const u32x2*>(row0 + 256 + l * 8);
        u32x2 vp0 = *reinterpret_cast<const u32x2*>(row0 + 384 + l * 8);
        u32x2 kk1 = *reinterpret_cast<const u32x2*>(row1 + 256 + l * 8);
        u32x2 vp1 = *reinterpret_cast<const u32x2*>(row1 + 384 + l * 8);
        float kf0[8], vf0[8], kf1[8], vf1[8];
        unpack_fp8x8(kk0, kf0); unpack_fp8x8(vp0, vf0);
        unpack_fp8x8(kk1, kf1); unpack_fp8x8(vp1, vf1);
        float dot0 = 0.f, dot1 = 0.f;
#pragma unroll
        for (int j = 0; j < 8; ++j) { dot0 += q[j] * kf0[j]; dot1 += q[j] * kf1[j]; }
#pragma unroll
        for (int t = 1; t < 16; t <<= 1) {
            dot0 += __shfl_xor(dot0, t, 16);
            dot1 += __shfl_xor(dot1, t, 16);
        }
        f32x2 b0 = __builtin_amdgcn_cvt_pk_f32_fp8((int)(rec0 & 0xFFu), false);
        f32x2 b1 = __builtin_amdgcn_cvt_pk_f32_fp8((int)(rec1 & 0xFFu), false);
        float p0 = __expf(fminf(dot0 * scale + b0[0], 60.f));
        float p1 = __expf(fminf(dot1 * scale + b1[0], 60.f));
        d += p0 + p1;
#pragma unroll
        for (int j = 0; j < 8; ++j) acc[j] += p0 * vf0[j] + p1 * vf1[j];
    }
    if (i < end) {
        unsigned rec = elist[i];
        const char* row = KV + (size_t)(rec >> 8) * 512;
        u32x2 kk = *reinterpret_cast<const u32x2*>(row + 256 + l * 8);
        u32x2 vp = *reinterpret_cast<const u32x2*>(row + 384 + l * 8);
        float kf[8], vf[8];
        unpack_fp8x8(kk, kf); unpack_fp8x8(vp, vf);
        float dot = 0.f;
#pragma unroll
        for (int j = 0; j < 8; ++j) dot += q[j] * kf[j];
#pragma unroll
        for (int t = 1; t < 16; t <<= 1) dot += __shfl_xor(dot, t, 16);
        f32x2 bt = __builtin_amdgcn_cvt_pk_f32_fp8((int)(rec & 0xFFu), false);
        float p = __expf(fminf(dot * scale + bt[0], 60.f));
        d += p;
#pragma unroll
        for (int j = 0; j < 8; ++j) acc[j] += p * vf[j];
    }
    float inv = 1.f / (d + 1e-8f);
    bf16x8 o;
#pragma unroll
    for (int j = 0; j < 8; ++j) o[j] = (__bf16)(acc[j] * inv);
    *reinterpret_cast<bf16x8*>(upd + l * 8) = o;   // permuted bf16 layout
}

// C = LayerNorm(X + A @ Wo^T + b), both node sets (64-row blocks, 256 thr).
// A (upd) bf16 with k-permuted cols; Wo16's k-dim identically permuted.
__global__ __launch_bounds__(256) void gemm_ln_both(
    const __bf16* __restrict__ upd_pro, const __bf16* __restrict__ upd_lig,
    const float* __restrict__ Xp, const float* __restrict__ Xl,
    const __bf16* __restrict__ W16,
    const float* __restrict__ bo_p, const float* __restrict__ g_p, const float* __restrict__ be_p,
    const float* __restrict__ bo_l, const float* __restrict__ g_l, const float* __restrict__ be_l,
    float* __restrict__ out_pro, float* __restrict__ out_lig,
    int Np, int Nl, int nbp)
{
    __shared__ char wlds[32768];
    int bid = blockIdx.x;
    int tid = threadIdx.x;
    int lane = tid & 63, wv = tid >> 6;
    int l15 = lane & 15, lg = lane >> 4;

    const __bf16* A; const float* X; const __bf16* Wo;
    const float *b, *g, *be_; float* C; int M, wrow;
    if (bid < nbp) {
        A = upd_pro; X = Xp; Wo = W16;
        b = bo_p; g = g_p; be_ = be_p; C = out_pro; M = Np; wrow = bid * 64 + wv * 16;
    } else {
        A = upd_lig; X = Xl; Wo = W16 + 16384;
        b = bo_l; g = g_l; be_ = be_l; C = out_lig; M = Nl; wrow = (bid - nbp) * 64 + wv * 16;
    }
    stage_w(Wo, wlds, tid);

    int r0 = wrow + l15; if (r0 > M - 1) r0 = M - 1;
    const __bf16* Arow0 = A + (size_t)r0 * 128 + lg * 8;
    bf16x8 a0[4];
#pragma unroll
    for (int ks = 0; ks < 4; ++ks)
        a0[ks] = *reinterpret_cast<const bf16x8*>(Arow0 + ks * 32);
    __syncthreads();

    f32x4 acc[8] = {};
#pragma unroll
    for (int ks = 0; ks < 4; ++ks) {
#pragma unroll
        for (int ni = 0; ni < 8; ++ni)
            acc[ni] = __builtin_amdgcn_mfma_f32_16x16x32_bf16(
                a0[ks], read_w(wlds, l15, lg, ni, ks), acc[ni], 0, 0, 0);
    }

    float bcol[8], gcol[8], becol[8];
#pragma unroll
    for (int ni = 0; ni < 8; ++ni) {
        bcol[ni]  = b[ni * 16 + l15];
        gcol[ni]  = g[ni * 16 + l15];
        becol[ni] = be_[ni * 16 + l15];
    }

#pragma unroll
    for (int r = 0; r < 4; ++r) {
        int row = wrow + lg * 4 + r;
        bool ok = row < M;
        int rowc = ok ? row : M - 1;
        float v[8];
#pragma unroll
        for (int ni = 0; ni < 8; ++ni) v[ni] = acc[ni][r] + bcol[ni];
        const float* Xr = X + (size_t)rowc * 128 + l15;
        float s1 = 0.f, s2 = 0.f;
#pragma unroll
        for (int ni = 0; ni < 8; ++ni) {
            v[ni] += Xr[ni * 16];
            s1 += v[ni]; s2 += v[ni] * v[ni];
        }
#pragma unroll
        for (int d = 1; d < 16; d <<= 1) {
            s1 += __shfl_xor(s1, d);
            s2 += __shfl_xor(s2, d);
        }
        float mu = s1 * 0.0078125f;
        float var = s2 * 0.0078125f - mu * mu;
        float rstd = rsqrtf(var + 1e-5f);
        if (ok) {
            float* Cr = C + (size_t)row * 128 + l15;
#pragma unroll
            for (int ni = 0; ni < 8; ++ni)
                Cr[ni * 16] = (v[ni] - mu) * rstd * gcol[ni] + becol[ni];
        }
    }
}

static inline int cdiv(int a, int b) { return (a + b - 1) / b; }

extern "C" void kernel_launch(void* const* d_in, const int* in_sizes, int n_in,
                              void* d_out, int out_size, void* d_ws, size_t ws_size,
                              hipStream_t stream)
{
    const float* pro_x  = (const float*)d_in[0];
    const float* lig_x  = (const float*)d_in[1];
    const int*   ei     = (const int*)d_in[2];
    const float* ea     = (const float*)d_in[3];
    const float* Wq_pro = (const float*)d_in[4];  const float* bq_pro = (const float*)d_in[5];
    const float* Wk_lig = (const float*)d_in[6];  const float* bk_lig = (const float*)d_in[7];
    const float* Wv_lig = (const float*)d_in[8];  const float* bv_lig = (const float*)d_in[9];
    const float* Wq_lig = (const float*)d_in[10]; const float* bq_lig = (const float*)d_in[11];
    const float* Wk_pro = (const float*)d_in[12]; const float* bk_pro = (const float*)d_in[13];
    const float* Wv_pro = (const float*)d_in[14]; const float* bv_pro = (const float*)d_in[15];
    const float* We     = (const float*)d_in[16];
    const float* Wo_pro = (const float*)d_in[17]; const float* bo_pro = (const float*)d_in[18];
    const float* Wo_lig = (const float*)d_in[19]; const float* bo_lig = (const float*)d_in[20];
    const float* g_pro  = (const float*)d_in[21]; const float* be_pro = (const float*)d_in[22];
    const float* g_lig  = (const float*)d_in[23]; const float* be_lig = (const float*)d_in[24];

    const int Np = in_sizes[0] / 128;
    const int Nl = in_sizes[1] / 128;
    const int E  = in_sizes[2] / 2;
    const int CE = in_sizes[3] / E;
    const int Nmax = Np > Nl ? Np : Nl;
    const int Ntot = Np + Nl;
    const int* pi = ei;
    const int* li = ei + E;

    float* out_pro = (float*)d_out;
    float* out_lig = out_pro + (size_t)Np * 128;

    float* ws = (float*)d_ws;
    size_t o = 0;
    char* QKVp = (char*)(ws + o); o += (size_t)Nmax * 128;       // [N][512B]
    char* QKVl = (char*)(ws + o); o += (size_t)Nmax * 128;
    float* bias = ws + o;   o += (size_t)E;
    unsigned* ranks = (unsigned*)(ws + o); o += (size_t)E;
    unsigned* elist = (unsigned*)(ws + o); o += 2 * (size_t)E;   // 2E x 4B
    int* counts = (int*)(ws + o); o += (size_t)Ntot + 8;
    int* offs   = (int*)(ws + o); o += (size_t)Ntot + 8;
    int* bsums  = (int*)(ws + o); o += 4096;
    unsigned char* W8 = (unsigned char*)(ws + o); o += 6 * 16384 / 4;  // [6][128][128] fp8
    __bf16* W16 = (__bf16*)(ws + o); o += 2 * 16384 / 2;         // [2][128][128] bf16 (Wo)
    __bf16* upd = (__bf16*)(ws + o); o += (size_t)Ntot * 64;     // permuted bf16
    __bf16* upd_pro = upd;
    __bf16* upd_lig = upd + (size_t)Np * 128;
    (void)ws_size; (void)n_in; (void)out_size;

    const float scale = 1.0f / sqrtf(128.0f);
    const int nEB = cdiv(E, 256);
    const int nEB4 = cdiv(E, 1024);

    (void)hipMemsetAsync(counts, 0, (size_t)(Ntot + 8) * sizeof(int), stream);
    // W8 order: 0=Wq_pro 1=Wk_pro 2=Wv_pro 3=Wq_lig 4=Wk_lig 5=Wv_lig
    cvt_bias_count<<<64 + nEB4, 256, 0, stream>>>(
        Wq_pro, Wk_pro, Wv_pro, Wq_lig, Wk_lig, Wv_lig, Wo_pro, Wo_lig,
        W8, W16, ea, We, pi, li, bias, counts, ranks, Np, E, CE);

    const int nb1 = cdiv(Ntot, 256);
    scan1<<<nb1, 256, 0, stream>>>(counts, offs, bsums, Ntot);
    scan3<<<nb1, 256, 0, stream>>>(offs, bsums, Ntot, 2 * E);

    const int nbp = cdiv(Np, 64), nbl = cdiv(Nl, 64);
    const int nbProj = nbp + nbl;
    proj_fill<<<nbProj + nEB, 256, 0, stream>>>(pro_x, lig_x, W8,
        bq_pro, bk_pro, bv_pro, bq_lig, bk_lig, bv_lig,
        QKVp, QKVl, pi, li, bias, ranks, offs, elist,
        Np, Nl, nbp, nbProj, E);

    attend<<<cdiv(Ntot, 16), 256, 0, stream>>>(QKVp, QKVl, elist, offs,
        upd_pro, upd_lig, Np, Ntot, scale);

    gemm_ln_both<<<nbp + nbl, 256, 0, stream>>>(upd_pro, upd_lig,
        pro_x, lig_x, W16, bo_pro, g_pro, be_pro, bo_lig, g_lig, be_lig,
        out_pro, out_lig, Np, Nl, nbp);
}

// Round 24
// 224.323 us; speedup vs baseline: 2.3841x; 1.0316x over previous
//
#include <hip/hip_runtime.h>
#include <float.h>
#include <math.h>

// ---------------------------------------------------------------------------
// EdgeGuidedCrossAttention, round 24 = R23 with proj_fill at 512 thr /
// 128 rows per block: one-shot 51KB W8 staging amortized over 2x rows, and
// 3 blocks/CU x 8 waves = ~24 waves/CU (vs ~9) to cover stage/A-load latency.
// fp8-weight projections (mfma fp8_fp8, stride-136 LDS, 0 bank conflicts);
// fill fused in (latency-bound scatter hides under proj); attend 2-way ILP;
// CSR atomic-free via ranks; upd bf16 k-permuted.
// Node table (512 B/row): Q bf16 [0,256) | K fp8 [256,384) | V fp8 [384,512).
// ---------------------------------------------------------------------------

typedef __bf16 bf16x8 __attribute__((ext_vector_type(8)));
typedef float  f32x4  __attribute__((ext_vector_type(4)));
typedef float  f32x2  __attribute__((ext_vector_type(2)));
typedef unsigned int u32x2 __attribute__((ext_vector_type(2)));

__device__ __forceinline__ u32x2 pack_fp8x8(const float* v) {
    int w0 = __builtin_amdgcn_cvt_pk_fp8_f32(v[0], v[1], 0, false);
    w0 = __builtin_amdgcn_cvt_pk_fp8_f32(v[2], v[3], w0, true);
    int w1 = __builtin_amdgcn_cvt_pk_fp8_f32(v[4], v[5], 0, false);
    w1 = __builtin_amdgcn_cvt_pk_fp8_f32(v[6], v[7], w1, true);
    u32x2 r; r[0] = (unsigned)w0; r[1] = (unsigned)w1;
    return r;
}

__device__ __forceinline__ void unpack_fp8x8(u32x2 p, float* out) {
    f32x2 t0 = __builtin_amdgcn_cvt_pk_f32_fp8((int)p[0], false);
    f32x2 t1 = __builtin_amdgcn_cvt_pk_f32_fp8((int)p[0], true);
    f32x2 t2 = __builtin_amdgcn_cvt_pk_f32_fp8((int)p[1], false);
    f32x2 t3 = __builtin_amdgcn_cvt_pk_f32_fp8((int)p[1], true);
    out[0] = t0[0]; out[1] = t0[1]; out[2] = t1[0]; out[3] = t1[1];
    out[4] = t2[0]; out[5] = t2[1]; out[6] = t3[0]; out[7] = t3[1];
}

__device__ __forceinline__ long pack_fp8x8_l(const float* v) {
    return __builtin_bit_cast(long, pack_fp8x8(v));
}

// Stage one [128][128] bf16 matrix into LDS with byte ^= ((row&7)<<4) swizzle.
__device__ __forceinline__ void stage_w(const __bf16* __restrict__ Ws, char* wlds, int tid) {
#pragma unroll
    for (int it = 0; it < 8; ++it) {
        int idx = it * 2048 + tid * 8;
        int byteoff = idx * 2;
        int row = byteoff >> 8;
        *reinterpret_cast<bf16x8*>(wlds + (byteoff ^ ((row & 7) << 4)))
            = *reinterpret_cast<const bf16x8*>(Ws + idx);
    }
}
__device__ __forceinline__ bf16x8 read_w(const char* wlds, int l15, int lg, int ni, int ks) {
    int row = ni * 16 + l15;
    int off = (row * 256 + ks * 64 + lg * 16) ^ ((row & 7) << 4);
    return *reinterpret_cast<const bf16x8*>(wlds + off);
}

// Stage one [128][128] fp8 matrix into LDS (512 threads, 4 x 8B each),
// row stride 136 B.
__device__ __forceinline__ void stage_w8_512(const unsigned char* __restrict__ W8m, char* dst, int tid) {
#pragma unroll
    for (int it = 0; it < 4; ++it) {
        int idx = it * 4096 + tid * 8;
        int row = idx >> 7, col = idx & 127;
        *reinterpret_cast<u32x2*>(dst + row * 136 + col)
            = *reinterpret_cast<const u32x2*>(W8m + idx);
    }
}
__device__ __forceinline__ long read_w8(const char* base, int l15, int lg, int ni, int ks) {
    int off = (ni * 16 + l15) * 136 + ks * 32 + lg * 8;
    return *reinterpret_cast<const long*>(base + off);
}

// Fused front kernel:
//   blocks [0,48): 6 QKV weight mats f32 -> fp8  (W8)
//   blocks [48,64): 2 Wo mats f32 -> bf16, k-dim permuted (W16)
//   blocks [64,..): bias + counts + ranks, 4 edges/thread (atomic MLP)
__global__ __launch_bounds__(256) void cvt_bias_count(
    const float* wq_p, const float* wk_p, const float* wv_p,
    const float* wq_l, const float* wk_l, const float* wv_l,
    const float* wo_p, const float* wo_l,
    unsigned char* __restrict__ W8, __bf16* __restrict__ W16,
    const float* __restrict__ ea, const float* __restrict__ We,
    const int* __restrict__ pi, const int* __restrict__ li,
    float* __restrict__ bias, int* __restrict__ counts,
    unsigned* __restrict__ ranks, int Np, int E, int CE)
{
    if (blockIdx.x < 48) {
        const float* srcs[6] = {wq_p, wk_p, wv_p, wq_l, wk_l, wv_l};
        int mat = blockIdx.x >> 3;
        int t = (blockIdx.x & 7) * 256 + threadIdx.x;
        int off = t * 8;
        float v[8];
        f32x4 lo = *reinterpret_cast<const f32x4*>(srcs[mat] + off);
        f32x4 hi = *reinterpret_cast<const f32x4*>(srcs[mat] + off + 4);
        v[0] = lo[0]; v[1] = lo[1]; v[2] = lo[2]; v[3] = lo[3];
        v[4] = hi[0]; v[5] = hi[1]; v[6] = hi[2]; v[7] = hi[3];
        *reinterpret_cast<u32x2*>(W8 + (size_t)mat * 16384 + off) = pack_fp8x8(v);
        return;
    }
    if (blockIdx.x < 64) {
        const float* srcs[2] = {wo_p, wo_l};
        int mat = (blockIdx.x - 48) >> 3;
        int t = ((blockIdx.x - 48) & 7) * 256 + threadIdx.x;
        int base = t * 8;
        const float* s = srcs[mat];
        __bf16* d = W16 + (size_t)mat * 16384;
#pragma unroll
        for (int u = 0; u < 8; ++u) {
            int idx = base + u;
            int row = idx >> 7, c = idx & 127;
            int pos = (c & 15) * 8 + (c >> 4);      // k-permuted
            d[row * 128 + pos] = (__bf16)s[idx];
        }
        return;
    }
    // 4 edges per thread (atomic MLP).
    int ebase = (blockIdx.x - 64) * 1024 + threadIdx.x;
    int ev[4]; int pv[4], lv[4]; float bv[4]; int r0v[4], r1v[4]; bool ok[4];
#pragma unroll
    for (int u = 0; u < 4; ++u) {
        int e = ebase + u * 256;
        ev[u] = e; ok[u] = e < E;
        if (ok[u]) { pv[u] = pi[e]; lv[u] = li[e]; }
    }
#pragma unroll
    for (int u = 0; u < 4; ++u) {
        if (ok[u]) {
            const float2* row = reinterpret_cast<const float2*>(ea + (size_t)ev[u] * CE);
            float acc = 0.f;
            int h = CE >> 1;
            for (int c = 0; c < h; ++c) {
                float2 v = row[c];
                acc += v.x * We[2 * c] + v.y * We[2 * c + 1];
            }
            if (CE & 1) acc += ea[(size_t)ev[u] * CE + CE - 1] * We[CE - 1];
            bv[u] = acc;
        }
    }
#pragma unroll
    for (int u = 0; u < 4; ++u)
        if (ok[u]) r0v[u] = atomicAdd(&counts[pv[u]], 1);
#pragma unroll
    for (int u = 0; u < 4; ++u)
        if (ok[u]) r1v[u] = atomicAdd(&counts[Np + lv[u]], 1);
#pragma unroll
    for (int u = 0; u < 4; ++u) {
        if (ok[u]) {
            bias[ev[u]] = bv[u];
            ranks[ev[u]] = (unsigned)(r0v[u] & 0xFFFF) | ((unsigned)r1v[u] << 16);
        }
    }
}

__global__ __launch_bounds__(256) void scan1(
    const int* __restrict__ counts, int* __restrict__ offs,
    int* __restrict__ bsums, int N)
{
    int idx = blockIdx.x * 256 + threadIdx.x;
    int v = (idx < N) ? counts[idx] : 0;
    int lane = threadIdx.x & 63, w = threadIdx.x >> 6;
    int x = v;
#pragma unroll
    for (int d = 1; d < 64; d <<= 1) {
        int y = __shfl_up(x, d);
        if (lane >= d) x += y;
    }
    __shared__ int wsum[4];
    if (lane == 63) wsum[w] = x;
    __syncthreads();
    int add = 0;
    for (int i = 0; i < w; ++i) add += wsum[i];
    x += add;
    if (idx < N) offs[idx] = x - v;
    if (threadIdx.x == 255) bsums[blockIdx.x] = x;
}

// scan3 with scan2 folded in: each block computes its prefix over raw bsums.
__global__ __launch_bounds__(256) void scan3(
    int* __restrict__ offs, const int* __restrict__ bsums, int N, int total)
{
    int b = blockIdx.x, t = threadIdx.x;
    int s = 0;
    for (int i = t; i < b; i += 256) s += bsums[i];
#pragma unroll
    for (int d = 1; d < 64; d <<= 1) s += __shfl_xor(s, d);
    __shared__ int ws_[4];
    if ((t & 63) == 0) ws_[t >> 6] = s;
    __syncthreads();
    int pre = ws_[0] + ws_[1] + ws_[2] + ws_[3];
    int idx = b * 256 + t;
    if (idx < N) offs[idx] += pre;
    if (idx == 0) offs[N] = total;
}

// Fused proj + fill launch (512 threads).
// Blocks [0, nbProj): fp8 QKV projection, 128 rows (8 waves x 16 rows), all
//   3 W mats staged once in 51 KB LDS, mfma fp8_fp8, 0 bank conflicts.
// Blocks [nbProj, ..): atomic-free CSR fill (512 edges/block).
__global__ __launch_bounds__(512) void proj_fill(
    const float* __restrict__ Xp, const float* __restrict__ Xl,
    const unsigned char* __restrict__ W8,
    const float* __restrict__ bq_p, const float* __restrict__ bk_p, const float* __restrict__ bv_p,
    const float* __restrict__ bq_l, const float* __restrict__ bk_l, const float* __restrict__ bv_l,
    char* __restrict__ QKVp, char* __restrict__ QKVl,
    const int* __restrict__ pi, const int* __restrict__ li,
    const float* __restrict__ bias, const unsigned* __restrict__ ranks,
    const int* __restrict__ offs, unsigned* __restrict__ elist,
    int Np, int Nl, int nbp, int nbProj, int E)
{
    __shared__ char wlds[52224];            // 3 x 128 x 136
    int bid = blockIdx.x;
    int tid = threadIdx.x;

    if (bid >= nbProj) {                    // ---- fill branch ----
        int e = (bid - nbProj) * 512 + tid;
        if (e >= E) return;
        int p = pi[e], l = li[e];
        unsigned rk = ranks[e];
        int w = __builtin_amdgcn_cvt_pk_fp8_f32(bias[e], 0.f, 0, false);
        unsigned b8 = (unsigned)w & 0xFFu;
        elist[offs[p] + (rk & 0xFFFFu)]  = ((unsigned)l << 8) | b8;
        elist[offs[Np + l] + (rk >> 16)] = ((unsigned)p << 8) | b8;
        return;
    }

    // ---- proj branch ----
    int lane = tid & 63, wv = tid >> 6;     // 8 waves
    int l15 = lane & 15, lg = lane >> 4;

    const float* A; const unsigned char* Wb8;
    const float* bsels[3]; char* QKV; int M, wrow;
    if (bid < nbp) {
        A = Xp; M = Np; wrow = bid * 128 + wv * 16;
        Wb8 = W8;                            // mats 0,1,2 = q,k,v (pro)
        bsels[0] = bq_p; bsels[1] = bk_p; bsels[2] = bv_p; QKV = QKVp;
    } else {
        A = Xl; M = Nl; wrow = (bid - nbp) * 128 + wv * 16;
        Wb8 = W8 + 3 * 16384;                // mats 3,4,5 = q,k,v (lig)
        bsels[0] = bq_l; bsels[1] = bk_l; bsels[2] = bv_l; QKV = QKVl;
    }

    stage_w8_512(Wb8 + 0 * 16384, wlds + 0 * 17408, tid);
    stage_w8_512(Wb8 + 1 * 16384, wlds + 1 * 17408, tid);
    stage_w8_512(Wb8 + 2 * 16384, wlds + 2 * 17408, tid);

    int r0 = wrow + l15; if (r0 > M - 1) r0 = M - 1;
    const float* Arow0 = A + (size_t)r0 * 128 + lg * 8;

    long a8[4];                              // A-frags fp8 (8 VGPR)
#pragma unroll
    for (int ks = 0; ks < 4; ++ks) {
        float v[8];
        f32x4 lo = *reinterpret_cast<const f32x4*>(Arow0 + ks * 32);
        f32x4 hi = *reinterpret_cast<const f32x4*>(Arow0 + ks * 32 + 4);
        v[0] = lo[0]; v[1] = lo[1]; v[2] = lo[2]; v[3] = lo[3];
        v[4] = hi[0]; v[5] = hi[1]; v[6] = hi[2]; v[7] = hi[3];
        a8[ks] = pack_fp8x8_l(v);
    }
    __syncthreads();

#pragma unroll
    for (int mat = 0; mat < 3; ++mat) {
        const char* wl = wlds + mat * 17408;
        f32x4 acc[8] = {};
#pragma unroll
        for (int ks = 0; ks < 4; ++ks) {
#pragma unroll
            for (int ni = 0; ni < 8; ++ni)
                acc[ni] = __builtin_amdgcn_mfma_f32_16x16x32_fp8_fp8(
                    a8[ks], read_w8(wl, l15, lg, ni, ks), acc[ni], 0, 0, 0);
        }
        float bc[8];
#pragma unroll
        for (int ni = 0; ni < 8; ++ni) bc[ni] = bsels[mat][ni * 16 + l15];
#pragma unroll
        for (int r = 0; r < 4; ++r) {
            int row = wrow + lg * 4 + r;
            if (row < M) {
                float v[8];              // col 16*ni+l15 -> stored pos l15*8+ni
#pragma unroll
                for (int ni = 0; ni < 8; ++ni) v[ni] = acc[ni][r] + bc[ni];
                char* rowb = QKV + (size_t)row * 512;
                if (mat == 0) {
                    bf16x8 o;
#pragma unroll
                    for (int ni = 0; ni < 8; ++ni) o[ni] = (__bf16)v[ni];
                    *reinterpret_cast<bf16x8*>(rowb + l15 * 16) = o;
                } else {
                    *reinterpret_cast<u32x2*>(rowb + 256 + (mat - 1) * 128 + l15 * 8)
                        = pack_fp8x8(v);
                }
            }
        }
    }
}

// One 16-lane group per target node (4 nodes/wave); 2-way edge ILP unroll.
// Lane holds 8 (permuted) dims; K,V fp8; 4B edge records; clamp at 60.
__global__ __launch_bounds__(256) void attend(
    const char* __restrict__ QKVp, const char* __restrict__ QKVl,
    const unsigned* __restrict__ elist, const int* __restrict__ offs,
    __bf16* __restrict__ upd_pro, __bf16* __restrict__ upd_lig,
    int Np, int Ntot, float scale)
{
    int node = blockIdx.x * 16 + (threadIdx.x >> 4);
    if (node >= Ntot) return;
    int l = threadIdx.x & 15;
    const char* Qrow; const char* KV; __bf16* upd;
    if (node < Np) {
        Qrow = QKVp + (size_t)node * 512; KV = QKVl;
        upd = upd_pro + (size_t)node * 128;
    } else {
        int n = node - Np;
        Qrow = QKVl + (size_t)n * 512; KV = QKVp;
        upd = upd_lig + (size_t)n * 128;
    }
    bf16x8 qv = *reinterpret_cast<const bf16x8*>(Qrow + l * 16);
    float q[8];
#pragma unroll
    for (int j = 0; j < 8; ++j) q[j] = (float)qv[j];

    int beg = offs[node], end = offs[node + 1];
    float d = 0.f;
    float acc[8] = {};
    int i = beg;
    for (; i + 1 < end; i += 2) {
        unsigned rec0 = elist[i], rec1 = elist[i + 1];
        const char* row0 = KV + (size_t)(rec0 >> 8) * 512;
        const char* row1 = KV + (size_t)(rec1 >> 8) * 512;
        u32x2 kk0 = *reinterpret_cast<const u32x2*>(row0 + 256 + l * 8);
        u32x2 vp0 = *reinterpret_cast<const u32x2*>(row0 + 384 + l * 8);
        u32x2 kk1 = *reinterpret_cast<const u32x2*>(row1 + 256 + l * 8);
        u32x2 vp1 = *reinterpret_cast<const u32x2*>(row1 + 384 + l * 8);
        float kf0[8], vf0[8], kf1[8], vf1[8];
        unpack_fp8x8(kk0, kf0); unpack_fp8x8(vp0, vf0);
        unpack_fp8x8(kk1, kf1); unpack_fp8x8(vp1, vf1);
        float dot0 = 0.f, dot1 = 0.f;
#pragma unroll
        for (int j = 0; j < 8; ++j) { dot0 += q[j] * kf0[j]; dot1 += q[j] * kf1[j]; }
#pragma unroll
        for (int t = 1; t < 16; t <<= 1) {
            dot0 += __shfl_xor(dot0, t, 16);
            dot1 += __shfl_xor(dot1, t, 16);
        }
        f32x2 b0 = __builtin_amdgcn_cvt_pk_f32_fp8((int)(rec0 & 0xFFu), false);
        f32x2 b1 = __builtin_amdgcn_cvt_pk_f32_fp8((int)(rec1 & 0xFFu), false);
        float p0 = __expf(fminf(dot0 * scale + b0[0], 60.f));
        float p1 = __expf(fminf(dot1 * scale + b1[0], 60.f));
        d += p0 + p1;
#pragma unroll
        for (int j = 0; j < 8; ++j) acc[j] += p0 * vf0[j] + p1 * vf1[j];
    }
    if (i < end) {
        unsigned rec = elist[i];
        const char* row = KV + (size_t)(rec >> 8) * 512;
        u32x2 kk = *reinterpret_cast<const u32x2*>(row + 256 + l * 8);
        u32x2 vp = *reinterpret_cast<const u32x2*>(row + 384 + l * 8);
        float kf[8], vf[8];
        unpack_fp8x8(kk, kf); unpack_fp8x8(vp, vf);
        float dot = 0.f;
#pragma unroll
        for (int j = 0; j < 8; ++j) dot += q[j] * kf[j];
#pragma unroll
        for (int t = 1; t < 16; t <<= 1) dot += __shfl_xor(dot, t, 16);
        f32x2 bt = __builtin_amdgcn_cvt_pk_f32_fp8((int)(rec & 0xFFu), false);
        float p = __expf(fminf(dot * scale + bt[0], 60.f));
        d += p;
#pragma unroll
        for (int j = 0; j < 8; ++j) acc[j] += p * vf[j];
    }
    float inv = 1.f / (d + 1e-8f);
    bf16x8 o;
#pragma unroll
    for (int j = 0; j < 8; ++j) o[j] = (__bf16)(acc[j] * inv);
    *reinterpret_cast<bf16x8*>(upd + l * 8) = o;   // permuted bf16 layout
}

// C = LayerNorm(X + A @ Wo^T + b), both node sets (64-row blocks, 256 thr).
// A (upd) bf16 with k-permuted cols; Wo16's k-dim identically permuted.
__global__ __launch_bounds__(256) void gemm_ln_both(
    const __bf16* __restrict__ upd_pro, const __bf16* __restrict__ upd_lig,
    const float* __restrict__ Xp, const float* __restrict__ Xl,
    const __bf16* __restrict__ W16,
    const float* __restrict__ bo_p, const float* __restrict__ g_p, const float* __restrict__ be_p,
    const float* __restrict__ bo_l, const float* __restrict__ g_l, const float* __restrict__ be_l,
    float* __restrict__ out_pro, float* __restrict__ out_lig,
    int Np, int Nl, int nbp)
{
    __shared__ char wlds[32768];
    int bid = blockIdx.x;
    int tid = threadIdx.x;
    int lane = tid & 63, wv = tid >> 6;
    int l15 = lane & 15, lg = lane >> 4;

    const __bf16* A; const float* X; const __bf16* Wo;
    const float *b, *g, *be_; float* C; int M, wrow;
    if (bid < nbp) {
        A = upd_pro; X = Xp; Wo = W16;
        b = bo_p; g = g_p; be_ = be_p; C = out_pro; M = Np; wrow = bid * 64 + wv * 16;
    } else {
        A = upd_lig; X = Xl; Wo = W16 + 16384;
        b = bo_l; g = g_l; be_ = be_l; C = out_lig; M = Nl; wrow = (bid - nbp) * 64 + wv * 16;
    }
    stage_w(Wo, wlds, tid);

    int r0 = wrow + l15; if (r0 > M - 1) r0 = M - 1;
    const __bf16* Arow0 = A + (size_t)r0 * 128 + lg * 8;
    bf16x8 a0[4];
#pragma unroll
    for (int ks = 0; ks < 4; ++ks)
        a0[ks] = *reinterpret_cast<const bf16x8*>(Arow0 + ks * 32);
    __syncthreads();

    f32x4 acc[8] = {};
#pragma unroll
    for (int ks = 0; ks < 4; ++ks) {
#pragma unroll
        for (int ni = 0; ni < 8; ++ni)
            acc[ni] = __builtin_amdgcn_mfma_f32_16x16x32_bf16(
                a0[ks], read_w(wlds, l15, lg, ni, ks), acc[ni], 0, 0, 0);
    }

    float bcol[8], gcol[8], becol[8];
#pragma unroll
    for (int ni = 0; ni < 8; ++ni) {
        bcol[ni]  = b[ni * 16 + l15];
        gcol[ni]  = g[ni * 16 + l15];
        becol[ni] = be_[ni * 16 + l15];
    }

#pragma unroll
    for (int r = 0; r < 4; ++r) {
        int row = wrow + lg * 4 + r;
        bool ok = row < M;
        int rowc = ok ? row : M - 1;
        float v[8];
#pragma unroll
        for (int ni = 0; ni < 8; ++ni) v[ni] = acc[ni][r] + bcol[ni];
        const float* Xr = X + (size_t)rowc * 128 + l15;
        float s1 = 0.f, s2 = 0.f;
#pragma unroll
        for (int ni = 0; ni < 8; ++ni) {
            v[ni] += Xr[ni * 16];
            s1 += v[ni]; s2 += v[ni] * v[ni];
        }
#pragma unroll
        for (int d = 1; d < 16; d <<= 1) {
            s1 += __shfl_xor(s1, d);
            s2 += __shfl_xor(s2, d);
        }
        float mu = s1 * 0.0078125f;
        float var = s2 * 0.0078125f - mu * mu;
        float rstd = rsqrtf(var + 1e-5f);
        if (ok) {
            float* Cr = C + (size_t)row * 128 + l15;
#pragma unroll
            for (int ni = 0; ni < 8; ++ni)
                Cr[ni * 16] = (v[ni] - mu) * rstd * gcol[ni] + becol[ni];
        }
    }
}

static inline int cdiv(int a, int b) { return (a + b - 1) / b; }

extern "C" void kernel_launch(void* const* d_in, const int* in_sizes, int n_in,
                              void* d_out, int out_size, void* d_ws, size_t ws_size,
                              hipStream_t stream)
{
    const float* pro_x  = (const float*)d_in[0];
    const float* lig_x  = (const float*)d_in[1];
    const int*   ei     = (const int*)d_in[2];
    const float* ea     = (const float*)d_in[3];
    const float* Wq_pro = (const float*)d_in[4];  const float* bq_pro = (const float*)d_in[5];
    const float* Wk_lig = (const float*)d_in[6];  const float* bk_lig = (const float*)d_in[7];
    const float* Wv_lig = (const float*)d_in[8];  const float* bv_lig = (const float*)d_in[9];
    const float* Wq_lig = (const float*)d_in[10]; const float* bq_lig = (const float*)d_in[11];
    const float* Wk_pro = (const float*)d_in[12]; const float* bk_pro = (const float*)d_in[13];
    const float* Wv_pro = (const float*)d_in[14]; const float* bv_pro = (const float*)d_in[15];
    const float* We     = (const float*)d_in[16];
    const float* Wo_pro = (const float*)d_in[17]; const float* bo_pro = (const float*)d_in[18];
    const float* Wo_lig = (const float*)d_in[19]; const float* bo_lig = (const float*)d_in[20];
    const float* g_pro  = (const float*)d_in[21]; const float* be_pro = (const float*)d_in[22];
    const float* g_lig  = (const float*)d_in[23]; const float* be_lig = (const float*)d_in[24];

    const int Np = in_sizes[0] / 128;
    const int Nl = in_sizes[1] / 128;
    const int E  = in_sizes[2] / 2;
    const int CE = in_sizes[3] / E;
    const int Nmax = Np > Nl ? Np : Nl;
    const int Ntot = Np + Nl;
    const int* pi = ei;
    const int* li = ei + E;

    float* out_pro = (float*)d_out;
    float* out_lig = out_pro + (size_t)Np * 128;

    float* ws = (float*)d_ws;
    size_t o = 0;
    char* QKVp = (char*)(ws + o); o += (size_t)Nmax * 128;       // [N][512B]
    char* QKVl = (char*)(ws + o); o += (size_t)Nmax * 128;
    float* bias = ws + o;   o += (size_t)E;
    unsigned* ranks = (unsigned*)(ws + o); o += (size_t)E;
    unsigned* elist = (unsigned*)(ws + o); o += 2 * (size_t)E;   // 2E x 4B
    int* counts = (int*)(ws + o); o += (size_t)Ntot + 8;
    int* offs   = (int*)(ws + o); o += (size_t)Ntot + 8;
    int* bsums  = (int*)(ws + o); o += 4096;
    unsigned char* W8 = (unsigned char*)(ws + o); o += 6 * 16384 / 4;  // [6][128][128] fp8
    __bf16* W16 = (__bf16*)(ws + o); o += 2 * 16384 / 2;         // [2][128][128] bf16 (Wo)
    __bf16* upd = (__bf16*)(ws + o); o += (size_t)Ntot * 64;     // permuted bf16
    __bf16* upd_pro = upd;
    __bf16* upd_lig = upd + (size_t)Np * 128;
    (void)ws_size; (void)n_in; (void)out_size;

    const float scale = 1.0f / sqrtf(128.0f);
    const int nEB4 = cdiv(E, 1024);

    (void)hipMemsetAsync(counts, 0, (size_t)(Ntot + 8) * sizeof(int), stream);
    // W8 order: 0=Wq_pro 1=Wk_pro 2=Wv_pro 3=Wq_lig 4=Wk_lig 5=Wv_lig
    cvt_bias_count<<<64 + nEB4, 256, 0, stream>>>(
        Wq_pro, Wk_pro, Wv_pro, Wq_lig, Wk_lig, Wv_lig, Wo_pro, Wo_lig,
        W8, W16, ea, We, pi, li, bias, counts, ranks, Np, E, CE);

    const int nb1 = cdiv(Ntot, 256);
    scan1<<<nb1, 256, 0, stream>>>(counts, offs, bsums, Ntot);
    scan3<<<nb1, 256, 0, stream>>>(offs, bsums, Ntot, 2 * E);

    const int nbp = cdiv(Np, 128), nbl = cdiv(Nl, 128);
    const int nbProj = nbp + nbl;
    proj_fill<<<nbProj + cdiv(E, 512), 512, 0, stream>>>(pro_x, lig_x, W8,
        bq_pro, bk_pro, bv_pro, bq_lig, bk_lig, bv_lig,
        QKVp, QKVl, pi, li, bias, ranks, offs, elist,
        Np, Nl, nbp, nbProj, E);

    attend<<<cdiv(Ntot, 16), 256, 0, stream>>>(QKVp, QKVl, elist, offs,
        upd_pro, upd_lig, Np, Ntot, scale);

    const int nbp2 = cdiv(Np, 64), nbl2 = cdiv(Nl, 64);
    gemm_ln_both<<<nbp2 + nbl2, 256, 0, stream>>>(upd_pro, upd_lig,
        pro_x, lig_x, W16, bo_pro, g_pro, be_pro, bo_lig, g_lig, be_lig,
        out_pro, out_lig, Np, Nl, nbp2);
}